// Round 5
// baseline (392.301 us; speedup 1.0000x reference)
//
#include <hip/hip_runtime.h>
#include <hip/hip_bf16.h>

typedef __attribute__((ext_vector_type(8))) short bf16x8;
typedef __attribute__((ext_vector_type(4))) short bf16x4;
typedef __attribute__((ext_vector_type(4))) float f32x4;
typedef __attribute__((address_space(3))) ushort lds_ushort;

#define MFMA32(a, b, c) __builtin_amdgcn_mfma_f32_16x16x32_bf16(a, b, c, 0, 0, 0)
#if __has_builtin(__builtin_amdgcn_mfma_f32_16x16x16bf16_1k)
#define HAVE_MFMA16K 1
#define MFMA16K(a, b, c) __builtin_amdgcn_mfma_f32_16x16x16bf16_1k(a, b, c, 0, 0, 0)
#else
#define HAVE_MFMA16K 0
#endif

// async global->LDS, 16B/lane; LDS dest = wave-uniform base + lane*16.
#define ASYNC16(g, l)                                                          \
    __builtin_amdgcn_global_load_lds(                                          \
        (const __attribute__((address_space(1))) unsigned int*)(g),            \
        (__attribute__((address_space(3))) unsigned int*)(l), 16, 0, 0)

// hw transpose read: per 16-lane group reads 128B window as 4x16 bf16
// row-major, lane l gets column (l&15). addr = window_base + (l&15)*8 bytes.
#define TR16(dst, addr, OFF)                                                   \
    asm volatile("ds_read_b64_tr_b16 %0, %1 offset:%2"                         \
                 : "=v"(dst) : "v"(addr), "i"(OFF))

__device__ __forceinline__ ushort f2bf(float f) {
    __hip_bfloat16 h = __float2bfloat16(f);  // RNE
    return *reinterpret_cast<ushort*>(&h);
}
// pack two f32 to bf16 pair in one instruction (T12; no builtin on gfx950).
__device__ __forceinline__ uint cvtpk(float a, float b) {
    uint r;
    asm("v_cvt_pk_bf16_f32 %0, %1, %2" : "=v"(r) : "v"(a), "v"(b));
    return r;
}

// log2(e)/sqrt(64), folded into Q projection -> attn does exp2(score) raw.
#define QSCALE 0.18033688011112042f

// ---------------------------------------------------------------------------
// fp32 -> bf16 convert (weights only; X converts inside gemm3).
// ---------------------------------------------------------------------------
struct CvtArgs { const float* s[4]; ushort* d[4]; int nb[4]; };

__global__ __launch_bounds__(256) void cvtk(CvtArgs a) {
    const int z = blockIdx.y;
    if ((int)blockIdx.x >= a.nb[z]) return;
    const float* s = a.s[z];
    ushort* d = a.d[z];
    const size_t i = (size_t)blockIdx.x * 2048 + threadIdx.x * 8;
    float4 f0 = *(const float4*)&s[i];
    float4 f1 = *(const float4*)&s[i + 4];
    *(ushort4*)&d[i]     = make_ushort4(f2bf(f0.x), f2bf(f0.y), f2bf(f0.z), f2bf(f0.w));
    *(ushort4*)&d[i + 4] = make_ushort4(f2bf(f1.x), f2bf(f1.y), f2bf(f1.z), f2bf(f1.w));
}

// ---------------------------------------------------------------------------
// NT GEMM, 128x64 tile (M x N), BK=32: out = (X@W^T + bias) * scale
//   xf32=1: X is fp32, staged raw via global_load_lds with XOR-swizzled
//           SOURCE (rule #21: linear LDS dest, involution on read side);
//           fragments converted in-reg with v_cvt_pk_bf16_f32.
//   mode 0: bf16 out [B=4,H=16,S=2048,64]  (Q scaled, K, V)
//   mode 2: fp32 out [8192,1024]           (final projection)
// R4: R3's reg-staged A was latency-bound (every __syncthreads drained the
// fresh loadA vmcnt -> ~500cy exposed per step, MfmaUtil 16%). DMA staging
// only ever has 1-step-old prefetch in flight at the barrier. 64-N tiles
// double the grid (3072/1024 wgs) -> ~4 blocks/CU for latency hiding.
// LDS 40KB/block. Bijective XCD swizzle for nwg=1024 (1024%8==0).
// ---------------------------------------------------------------------------
struct GemmArgs {
    const ushort* X[3]; const float* Xf[3]; const ushort* W[3];
    const float* B[3]; void* O[3]; int mode[3]; int xf32[3]; float scale[3];
};

__global__ __launch_bounds__(256) void gemm3(GemmArgs g) {
    // Asf: fp32 view [2][128][32] floats (32KB). bf16 path uses the first
    // 8KB of each buffer as ushort[128][32]. Bs: bf16 [2][64][32] (8KB).
    __shared__ __attribute__((aligned(16))) float  Asf[2][128][32];
    __shared__ __attribute__((aligned(16))) ushort Bs[2][64][32];

    const int z = blockIdx.z;
    const ushort* __restrict__ W = g.W[z];
    const float*  __restrict__ bias = g.B[z];
    const int mode = g.mode[z];
    const float scale = g.scale[z];

    const int tid  = threadIdx.x;
    const int lane = tid & 63;
    const int wave = tid >> 6;
    const int quad = lane >> 4;
    const int l16  = lane & 15;
    const int wm   = (wave >> 1) * 64;   // wave covers 64 M rows
    const int wn   = (wave & 1) * 32;    // wave covers 32 N cols

    const int flat = blockIdx.x + 16 * blockIdx.y;          // hw linear id
    const int t    = (flat & 7) * 128 + (flat >> 3);        // bijective XCD map
    const int m0   = (t >> 4) * 128;
    const int n0   = (t & 15) * 64;

    f32x4 acc[4][2];
#pragma unroll
    for (int i = 0; i < 4; i++)
#pragma unroll
        for (int j = 0; j < 2; j++) acc[i][j] = (f32x4)0.0f;

    // B staging: 64x32 bf16 = 4KB = 256 chunks of 16B -> 1 ASYNC16/thread.
    auto stageB = [&](int buf, int k0) {
        const int row = tid >> 2, colq = tid & 3;
        ASYNC16(&W[(size_t)(n0 + row) * 1024 + k0 + colq * 8],
                &Bs[buf][0][0] + (size_t)(wave * 64) * 8);
    };

    if (g.xf32[z]) {
        // ==== fused-cvt path: raw fp32 A via DMA, swizzled source ====
        const float* __restrict__ Xf = g.Xf[z];
        // 128x32 fp32 = 16KB = 1024 chunks -> 4 ASYNC16/thread.
        // chunk c: row=c>>3, group g=c&7 (4 floats); LDS[row][g] holds
        // global group g^(row&7) -> read side XORs the same.
        auto stageA = [&](int buf, int k0) {
#pragma unroll
            for (int j = 0; j < 4; j++) {
                const int c    = j * 256 + tid;
                const int row  = c >> 3;
                const int srcg = (c & 7) ^ (row & 7);
                ASYNC16(&Xf[(size_t)(m0 + row) * 1024 + k0 + srcg * 4],
                        &Asf[buf][0][0] + (size_t)(j * 256 + wave * 64) * 4);
            }
        };

        stageA(0, 0);
        stageB(0, 0);
        int cur = 0;
        for (int k0 = 0; k0 < 1024; k0 += 32) {
            __syncthreads();  // drains 1-step-old prefetch only
            if (k0 + 32 < 1024) {
                stageA(cur ^ 1, k0 + 32);
                stageB(cur ^ 1, k0 + 32);
            }
            const int sw = l16 & 7;
            bf16x8 af[4], bfr[2];
#pragma unroll
            for (int i = 0; i < 4; i++) {
                const int row = wm + i * 16 + l16;
                f32x4 f0 = *(const f32x4*)&Asf[cur][row][((quad * 2) ^ sw) * 4];
                f32x4 f1 = *(const f32x4*)&Asf[cur][row][((quad * 2 + 1) ^ sw) * 4];
                union { uint u[4]; bf16x8 v; } p;
                p.u[0] = cvtpk(f0[0], f0[1]);
                p.u[1] = cvtpk(f0[2], f0[3]);
                p.u[2] = cvtpk(f1[0], f1[1]);
                p.u[3] = cvtpk(f1[2], f1[3]);
                af[i] = p.v;
            }
#pragma unroll
            for (int j = 0; j < 2; j++)
                bfr[j] = *(const bf16x8*)&Bs[cur][wn + j * 16 + l16][quad * 8];
#pragma unroll
            for (int i = 0; i < 4; i++)
#pragma unroll
                for (int j = 0; j < 2; j++)
                    acc[i][j] = MFMA32(af[i], bfr[j], acc[i][j]);
            cur ^= 1;
        }
    } else {
        // ==== bf16 path: both sides DMA (out-projection) ====
        const ushort* __restrict__ X = g.X[z];
        ushort* As0 = (ushort*)&Asf[0][0][0];
        ushort* As1 = (ushort*)&Asf[1][0][0];
        // 128x32 bf16 = 8KB = 512 chunks -> 2 ASYNC16/thread.
        auto stageA = [&](int buf, int k0) {
            ushort* dst = buf ? As1 : As0;
#pragma unroll
            for (int j = 0; j < 2; j++) {
                const int c   = j * 256 + tid;
                const int row = c >> 2;
                const int col = (c & 3) * 8;
                ASYNC16(&X[(size_t)(m0 + row) * 1024 + k0 + col],
                        dst + (size_t)(j * 256 + wave * 64) * 8);
            }
        };
        stageA(0, 0);
        stageB(0, 0);
        int cur = 0;
        for (int k0 = 0; k0 < 1024; k0 += 32) {
            __syncthreads();
            if (k0 + 32 < 1024) {
                stageA(cur ^ 1, k0 + 32);
                stageB(cur ^ 1, k0 + 32);
            }
            const ushort* As = cur ? As1 : As0;
            bf16x8 af[4], bfr[2];
#pragma unroll
            for (int i = 0; i < 4; i++)
                af[i] = *(const bf16x8*)&As[(size_t)(wm + i * 16 + l16) * 32 + quad * 8];
#pragma unroll
            for (int j = 0; j < 2; j++)
                bfr[j] = *(const bf16x8*)&Bs[cur][wn + j * 16 + l16][quad * 8];
#pragma unroll
            for (int i = 0; i < 4; i++)
#pragma unroll
                for (int j = 0; j < 2; j++)
                    acc[i][j] = MFMA32(af[i], bfr[j], acc[i][j]);
            cur ^= 1;
        }
    }

    // C/D: col = lane&15 (n), row = quad*4 + reg (m).
#pragma unroll
    for (int i = 0; i < 4; i++) {
#pragma unroll
        for (int j = 0; j < 2; j++) {
            const int n  = n0 + wn + j * 16 + l16;
            const float bb = bias[n];
#pragma unroll
            for (int r = 0; r < 4; r++) {
                const int m = m0 + wm + i * 16 + quad * 4 + r;
                const float val = (acc[i][j][r] + bb) * scale;
                if (mode == 2) {
                    ((float*)g.O[z])[(size_t)m * 1024 + n] = val;
                } else {
                    const int bat = m >> 11, s = m & 2047, h = n >> 6, d = n & 63;
                    ((ushort*)g.O[z])[((size_t)((bat * 16 + h) * 2048 + s)) * 64 + d]
                        = f2bf(val);
                }
            }
        }
    }
}

// ---------------------------------------------------------------------------
// Attention, P-in-registers (unchanged from R2; 97% combined pipe util).
// ---------------------------------------------------------------------------
__global__ __launch_bounds__(256, 4) void attn(
    const ushort* __restrict__ Qp, const ushort* __restrict__ Kp,
    const ushort* __restrict__ Vp, ushort* __restrict__ ctx)
{
    __shared__ __attribute__((aligned(16))) ushort Ks[2][2 * 64 * 32];  // 2x8KB
    __shared__ __attribute__((aligned(16))) ushort Vs[2][64 * 64];      // 2x8KB

    const int tid  = threadIdx.x;
    const int lane = tid & 63;
    const int wave = tid >> 6;
    const int quad = lane >> 4;
    const int l16  = lane & 15;

    const int id = blockIdx.x;
    const int bh = (id & 7) * 8 + ((id >> 3) & 7);  // XCD-contiguous bh
    const int q0 = (id >> 6) * 128;
    const int b  = bh >> 4, h = bh & 15;

    const ushort* Qg = Qp + ((size_t)bh * 2048 + q0) * 64;
    const ushort* Kg = Kp + (size_t)bh * 2048 * 64;
    const ushort* Vg = Vp + (size_t)bh * 2048 * 64;

    // Loop-invariant Q fragments (B-operand: n=l16=query, k=quad*8+e).
    bf16x8 aq[2][2];
#pragma unroll
    for (int st = 0; st < 2; st++)
#pragma unroll
        for (int kk = 0; kk < 2; kk++)
            aq[st][kk] = *(const bf16x8*)&Qg[(size_t)(wave * 32 + st * 16 + l16) * 64
                                            + kk * 32 + quad * 8];

    f32x4 o[2][4];
#pragma unroll
    for (int st = 0; st < 2; st++)
#pragma unroll
        for (int jd = 0; jd < 4; jd++) o[st][jd] = (f32x4)0.0f;
#if HAVE_MFMA16K
    f32x4 ls[2] = {(f32x4)0.0f, (f32x4)0.0f};  // row sums, o-compatible layout
    union { uint u[2]; bf16x4 v; } ones;
    ones.u[0] = 0x3F803F80u; ones.u[1] = 0x3F803F80u;  // bf16 1.0 x4
#else
    float lsum[2] = {0.f, 0.f};
#endif

    // K tile: natural [half][row][32] layout. V tile: 4x16-subtiled V' via
    // source-swizzled async chunks; global src stays 128B-coalesced per 8 lanes.
    auto stage = [&](int buf, int n0) {
#pragma unroll
        for (int j = 0; j < 2; j++) {
            const int c    = j * 256 + tid;
            const int colq = c & 3;
            const int row  = (c >> 2) & 63;
            const int half = c >> 8;
            ASYNC16(&Kg[(size_t)(n0 + row) * 64 + half * 32 + colq * 8],
                    &Ks[buf][0] + (size_t)(j * 256 + wave * 64) * 8);
        }
#pragma unroll
        for (int j = 0; j < 2; j++) {
            const int c   = j * 256 + tid;
            const int key = ((c >> 5) << 2) | ((c >> 1) & 3);
            const int d   = (((c >> 3) & 3) << 4) | ((c & 1) << 3);
            ASYNC16(&Vg[(size_t)(n0 + key) * 64 + d],
                    &Vs[buf][0] + (size_t)(j * 256 + wave * 64) * 8);
        }
    };

    stage(0, 0);
    int cur = 0;

    for (int n0 = 0; n0 < 2048; n0 += 64) {
        __syncthreads();  // drains vmcnt: buf 'cur' is ready; prev reads done
        if (n0 + 64 < 2048) stage(cur ^ 1, n0 + 64);  // flies under compute

        // ---- S^T: 8 tiles (kb keys x st strips), exp2 + pack in-register ----
        uint pk[4][2][2];
#pragma unroll
        for (int kb = 0; kb < 4; kb++) {
            bf16x8 kf0 = *(const bf16x8*)&Ks[cur][(size_t)(kb * 16 + l16) * 32 + quad * 8];
            bf16x8 kf1 = *(const bf16x8*)&Ks[cur][(size_t)(64 + kb * 16 + l16) * 32 + quad * 8];
#pragma unroll
            for (int st = 0; st < 2; st++) {
                f32x4 s = (f32x4)0.0f;
                s = MFMA32(kf0, aq[st][0], s);
                s = MFMA32(kf1, aq[st][1], s);
                float e0 = __builtin_amdgcn_exp2f(s[0]);
                float e1 = __builtin_amdgcn_exp2f(s[1]);
                float e2 = __builtin_amdgcn_exp2f(s[2]);
                float e3 = __builtin_amdgcn_exp2f(s[3]);
                pk[kb][st][0] = cvtpk(e0, e1);
                pk[kb][st][1] = cvtpk(e2, e3);
#if !HAVE_MFMA16K
                lsum[st] += (e0 + e1) + (e2 + e3);
#endif
            }
        }

#if HAVE_MFMA16K
        // ---- PV: B-frags via hw transpose reads from subtiled V' ----
        const lds_ushort* vp = (const lds_ushort*)&Vs[cur][0] + quad * 256 + l16 * 4;
        bf16x4 vf[4][4];  // [jd][kb]
#define TRISSUE(JD)                                                            \
        TR16(vf[JD][0], vp, (JD) * 128 + 0);                                   \
        TR16(vf[JD][1], vp, (JD) * 128 + 2048);                                \
        TR16(vf[JD][2], vp, (JD) * 128 + 4096);                                \
        TR16(vf[JD][3], vp, (JD) * 128 + 6144);
        TRISSUE(0) TRISSUE(1) TRISSUE(2) TRISSUE(3)

        // Row-sum MFMAs (register-only) fill the tr-read latency window:
        // C[q][*] += sum_k P[q][k]; reg r holds query quad*4+r = o's layout.
#pragma unroll
        for (int kb = 0; kb < 4; kb++) {
#pragma unroll
            for (int st = 0; st < 2; st++) {
                union { uint u[2]; bf16x4 v; } pf;
                pf.u[0] = pk[kb][st][0];
                pf.u[1] = pk[kb][st][1];
                ls[st] = MFMA16K(pf.v, ones.v, ls[st]);
            }
        }

        // counted lgkmcnt: jd group ready when <=12-4*jd outstanding (FIFO,
        // trs are oldest). sched_barrier(0) after each wait (rule #18).
#define PVWAIT(N)                                                              \
        asm volatile("s_waitcnt lgkmcnt(" #N ")" ::: "memory");                \
        __builtin_amdgcn_sched_barrier(0);
#define PVJD(JD)                                                               \
        _Pragma("unroll")                                                      \
        for (int kb = 0; kb < 4; kb++) {                                       \
            _Pragma("unroll")                                                  \
            for (int st = 0; st < 2; st++) {                                   \
                union { uint u[2]; bf16x4 v; } pf;                             \
                pf.u[0] = pk[kb][st][0];                                       \
                pf.u[1] = pk[kb][st][1];                                       \
                o[st][JD] = MFMA16K(pf.v, vf[JD][kb], o[st][JD]);              \
            }                                                                  \
        }
        __builtin_amdgcn_s_setprio(1);
        PVWAIT(12) PVJD(0)
        PVWAIT(8)  PVJD(1)
        PVWAIT(4)  PVJD(2)
        PVWAIT(0)  PVJD(3)
        __builtin_amdgcn_s_setprio(0);
#else
        // Fallback: assemble K=32 A-frags via ds_bpermute, gather V from the
        // subtiled V' with scalar reads, PV with MFMA32. (Correctness path.)
        const int addr0 = 4 * ((2 * (quad & 1)) * 16 + l16);
        const int addr1 = addr0 + 64;
#pragma unroll
        for (int kt = 0; kt < 2; kt++) {
            bf16x8 apf[2];
#pragma unroll
            for (int st = 0; st < 2; st++) {
                union { uint u[4]; bf16x8 v; } t;
#pragma unroll
                for (int j = 0; j < 4; j++) {
                    uint src = (quad & 2) ? pk[kt * 2 + 1][st][j & 1]
                                          : pk[kt * 2][st][j & 1];
                    t.u[j] = (uint)__builtin_amdgcn_ds_bpermute(
                        (j >> 1) ? addr1 : addr0, (int)src);
                }
                apf[st] = t.v;
            }
#pragma unroll
            for (int jd = 0; jd < 4; jd++) {
                union { ushort s[8]; bf16x8 v; } vv;
#pragma unroll
                for (int e = 0; e < 8; e++) {
                    const int key = kt * 32 + quad * 8 + e;
                    const int d   = jd * 16 + l16;
                    vv.s[e] = Vs[cur][(key >> 2) * 256 + (d >> 4) * 64
                                      + (key & 3) * 16 + (d & 15)];
                }
#pragma unroll
                for (int st = 0; st < 2; st++)
                    o[st][jd] = MFMA32(apf[st], vv.v, o[st][jd]);
            }
        }
#endif
        cur ^= 1;
    }

#if HAVE_MFMA16K
    // ls[st][r] is already the row sum for query quad*4+r — no shuffles.
#pragma unroll
    for (int st = 0; st < 2; st++) {
        float inv[4];
#pragma unroll
        for (int r = 0; r < 4; r++) inv[r] = 1.0f / ls[st][r];
#pragma unroll
        for (int jd = 0; jd < 4; jd++) {
#pragma unroll
            for (int r = 0; r < 4; r++) {
                const int s = q0 + wave * 32 + st * 16 + quad * 4 + r;
                ctx[((size_t)(b * 2048 + s)) * 1024 + h * 64 + jd * 16 + l16] =
                    f2bf(o[st][jd][r] * inv[r]);
            }
        }
    }
#else
    // lsum holds per-(l16,quad) partials for query=l16: reduce over quads.
#pragma unroll
    for (int st = 0; st < 2; st++) {
        float lsv = lsum[st];
        lsv += __shfl_xor(lsv, 16, 64);
        lsv += __shfl_xor(lsv, 32, 64);
        float inv[4];
#pragma unroll
        for (int r = 0; r < 4; r++)
            inv[r] = 1.0f / __shfl(lsv, quad * 4 + r, 64);
#pragma unroll
        for (int jd = 0; jd < 4; jd++) {
#pragma unroll
            for (int r = 0; r < 4; r++) {
                const int s = q0 + wave * 32 + st * 16 + quad * 4 + r;
                ctx[((size_t)(b * 2048 + s)) * 1024 + h * 64 + jd * 16 + l16] =
                    f2bf(o[st][jd][r] * inv[r]);
            }
        }
    }
#endif
}

extern "C" void kernel_launch(void* const* d_in, const int* in_sizes, int n_in,
                              void* d_out, int out_size, void* d_ws, size_t ws_size,
                              hipStream_t stream) {
    const float* q    = (const float*)d_in[0];
    const float* k    = (const float*)d_in[1];
    const float* v    = (const float*)d_in[2];
    const float* wq_w = (const float*)d_in[3];
    const float* wq_b = (const float*)d_in[4];
    const float* wk_w = (const float*)d_in[5];
    const float* wk_b = (const float*)d_in[6];
    const float* wv_w = (const float*)d_in[7];
    const float* wv_b = (const float*)d_in[8];
    const float* wo_w = (const float*)d_in[9];
    const float* wo_b = (const float*)d_in[10];
    float* out = (float*)d_out;

    const size_t NE = (size_t)4 * 2048 * 1024;
    const size_t NW = (size_t)1024 * 1024;
    const size_t need_fused = (4 * NE + 4 * NW) * 2;

    dim3 blk(256);

    if (ws_size >= need_fused) {
        ushort* Wq = (ushort*)d_ws;
        ushort* Wk = Wq + NW;
        ushort* Wv = Wk + NW;
        ushort* Wo = Wv + NW;
        ushort* Qp = Wo + NW;
        ushort* Kp = Qp + NE;
        ushort* Vp = Kp + NE;
        ushort* ctx = Vp + NE;

        CvtArgs ca;
        ca.s[0]=wq_w; ca.d[0]=Wq; ca.nb[0]=512;
        ca.s[1]=wk_w; ca.d[1]=Wk; ca.nb[1]=512;
        ca.s[2]=wv_w; ca.d[2]=Wv; ca.nb[2]=512;
        ca.s[3]=wo_w; ca.d[3]=Wo; ca.nb[3]=512;
        cvtk<<<dim3(512, 4), blk, 0, stream>>>(ca);

        GemmArgs ga;
        ga.Xf[0]=q; ga.Xf[1]=k; ga.Xf[2]=v;
        ga.X[0]=ga.X[1]=ga.X[2]=nullptr;
        ga.W[0]=Wq; ga.W[1]=Wk; ga.W[2]=Wv;
        ga.B[0]=wq_b; ga.B[1]=wk_b; ga.B[2]=wv_b;
        ga.O[0]=Qp; ga.O[1]=Kp; ga.O[2]=Vp;
        ga.mode[0]=ga.mode[1]=ga.mode[2]=0;
        ga.xf32[0]=ga.xf32[1]=ga.xf32[2]=1;
        ga.scale[0]=QSCALE; ga.scale[1]=1.0f; ga.scale[2]=1.0f;
        gemm3<<<dim3(16, 64, 3), blk, 0, stream>>>(ga);

        attn<<<dim3(1024), blk, 0, stream>>>(Qp, Kp, Vp, ctx);

        GemmArgs go;
        for (int i = 0; i < 3; i++) {
            go.X[i]=ctx; go.Xf[i]=nullptr; go.W[i]=Wo; go.B[i]=wo_b;
            go.O[i]=out; go.mode[i]=2; go.xf32[i]=0; go.scale[i]=1.0f;
        }
        gemm3<<<dim3(16, 64, 1), blk, 0, stream>>>(go);
    } else {
        // Serial fallback: one W buffer reused (needs (4NE+NW)*2 = 66 MB).
        ushort* Qp  = (ushort*)d_ws;
        ushort* Kp  = Qp + NE;
        ushort* Vp  = Kp + NE;
        ushort* ctx = Vp + NE;
        ushort* Wb  = ctx + NE;

        const float* xs[3] = {q, k, v};
        const float* ws[3] = {wq_w, wk_w, wv_w};
        const float* bs[3] = {wq_b, wk_b, wv_b};
        ushort* os[3] = {Qp, Kp, Vp};
        for (int p = 0; p < 3; p++) {
            CvtArgs c;
            c.s[0]=ws[p]; c.d[0]=Wb; c.nb[0]=512;
            for (int i = 1; i < 4; i++) { c.s[i]=ws[p]; c.d[i]=Wb; c.nb[i]=0; }
            cvtk<<<dim3(512, 1), blk, 0, stream>>>(c);
            GemmArgs gg;
            for (int i = 0; i < 3; i++) {
                gg.Xf[i]=xs[p]; gg.X[i]=nullptr; gg.W[i]=Wb; gg.B[i]=bs[p];
                gg.O[i]=os[p]; gg.mode[i]=0; gg.xf32[i]=1;
                gg.scale[i]=(p == 0) ? QSCALE : 1.0f;
            }
            gemm3<<<dim3(16, 64, 1), blk, 0, stream>>>(gg);
        }

        attn<<<dim3(1024), blk, 0, stream>>>(Qp, Kp, Vp, ctx);

        CvtArgs c;
        c.s[0]=wo_w; c.d[0]=Wb; c.nb[0]=512;
        for (int i = 1; i < 4; i++) { c.s[i]=wo_w; c.d[i]=Wb; c.nb[i]=0; }
        cvtk<<<dim3(512, 1), blk, 0, stream>>>(c);
        GemmArgs go;
        for (int i = 0; i < 3; i++) {
            go.X[i]=ctx; go.Xf[i]=nullptr; go.W[i]=Wb; go.B[i]=wo_b;
            go.O[i]=out; go.mode[i]=2; go.xf32[i]=0; go.scale[i]=1.0f;
        }
        gemm3<<<dim3(16, 64, 1), blk, 0, stream>>>(go);
    }
}

// Round 6
// 345.064 us; speedup vs baseline: 1.1369x; 1.1369x over previous
//
#include <hip/hip_runtime.h>
#include <hip/hip_bf16.h>

typedef __attribute__((ext_vector_type(8))) short bf16x8;
typedef __attribute__((ext_vector_type(4))) short bf16x4;
typedef __attribute__((ext_vector_type(4))) float f32x4;
typedef __attribute__((address_space(3))) ushort lds_ushort;

#define MFMA32(a, b, c) __builtin_amdgcn_mfma_f32_16x16x32_bf16(a, b, c, 0, 0, 0)
#if __has_builtin(__builtin_amdgcn_mfma_f32_16x16x16bf16_1k)
#define HAVE_MFMA16K 1
#define MFMA16K(a, b, c) __builtin_amdgcn_mfma_f32_16x16x16bf16_1k(a, b, c, 0, 0, 0)
#else
#define HAVE_MFMA16K 0
#endif

// async global->LDS, 16B/lane; LDS dest = wave-uniform base + lane*16.
#define ASYNC16(g, l)                                                          \
    __builtin_amdgcn_global_load_lds(                                          \
        (const __attribute__((address_space(1))) unsigned int*)(g),            \
        (__attribute__((address_space(3))) unsigned int*)(l), 16, 0, 0)

// hw transpose read: per 16-lane group reads 128B window as 4x16 bf16
// row-major, lane l gets column (l&15). addr = window_base + (l&15)*8 bytes.
#define TR16(dst, addr, OFF)                                                   \
    asm volatile("ds_read_b64_tr_b16 %0, %1 offset:%2"                         \
                 : "=v"(dst) : "v"(addr), "i"(OFF))

__device__ __forceinline__ ushort f2bf(float f) {
    __hip_bfloat16 h = __float2bfloat16(f);  // RNE
    return *reinterpret_cast<ushort*>(&h);
}
// pack two f32 to bf16 pair in one instruction (T12; no builtin on gfx950).
__device__ __forceinline__ uint cvtpk(float a, float b) {
    uint r;
    asm("v_cvt_pk_bf16_f32 %0, %1, %2" : "=v"(r) : "v"(a), "v"(b));
    return r;
}

// log2(e)/sqrt(64), folded into Q projection -> attn does exp2(score) raw.
#define QSCALE 0.18033688011112042f

// ---------------------------------------------------------------------------
// fp32 -> bf16 convert, multi-range (q,k,v + 4 weights).
// ---------------------------------------------------------------------------
struct CvtArgs { const float* s[7]; ushort* d[7]; int nb[7]; };

__global__ __launch_bounds__(256) void cvtk(CvtArgs a) {
    const int z = blockIdx.y;
    if ((int)blockIdx.x >= a.nb[z]) return;
    const float* s = a.s[z];
    ushort* d = a.d[z];
    const size_t i = (size_t)blockIdx.x * 2048 + threadIdx.x * 8;
    float4 f0 = *(const float4*)&s[i];
    float4 f1 = *(const float4*)&s[i + 4];
    *(ushort4*)&d[i]     = make_ushort4(f2bf(f0.x), f2bf(f0.y), f2bf(f0.z), f2bf(f0.w));
    *(ushort4*)&d[i + 4] = make_ushort4(f2bf(f1.x), f2bf(f1.y), f2bf(f1.z), f2bf(f1.w));
}

// ---------------------------------------------------------------------------
// 256x256 8-phase bf16 NT GEMM (m201 template port): out = (X@W^T + b)*scale
//   mode 0: bf16 out [B=4,H=16,S=2048,64]  (Q scaled, K, V)
//   mode 2: fp32 out [8192,1024]           (final projection)
// Geometry: BM=BN=256, BK=64, 16 K-tiles (K=1024), 512 thr = 8 waves (2Mx4N),
// per-wave 128x64 out = acc[8][4] f32x4. LDS 128KB dynamic: A[2][256][64],
// B[2][256][64] bf16. Half-tile = 128 rows x 64 k = 16KB = 2 ASYNC16/thread.
// Issue sequence: half s (order B0,B1,A0,A1 per tile) issued at phase s-6
// (6-phase lead); 4 phases/tile, each: {issue 1 half || ds_read A-quadrant
// (+8 B-frag reads at p0)} -> barrier -> lgkmcnt(0) -> setprio(1) -> 16 MFMA
// -> setprio(0) -> [vmcnt(4) at p3] -> barrier. vmcnt never 0 in loop: 2
// halves stay in flight across every tile boundary (T4). Clobber-safety:
// tile t+2's DMA into buf[t&1] is issued >=2 barrier-phases after that
// region's last read. Bank swizzle (T2): physical 16B-group = logical ^
// (row&7), applied on DMA source and on reads (row&7 == l16&7 at all read
// sites) -> balanced 8 lanes/bank-group. XCD swizzle: 128 wgs/z, xcd=flat%8.
// ---------------------------------------------------------------------------
struct GemmArgs {
    const ushort* X[3]; const ushort* W[3]; const float* B[3];
    void* O[3]; int mode[3]; float scale[3];
};

__global__ __launch_bounds__(512, 2) void gemm256(GemmArgs g) {
    extern __shared__ __attribute__((aligned(16))) ushort smem[];
    // layout: A bufs [2][16384], then B bufs [2][16384] (ushorts)

    const int z = blockIdx.z;
    const ushort* __restrict__ X = g.X[z];
    const ushort* __restrict__ W = g.W[z];
    const float*  __restrict__ bias = g.B[z];
    const int mode = g.mode[z];
    const float scale = g.scale[z];

    const int tid  = threadIdx.x;
    const int lane = tid & 63;
    const int wave = tid >> 6;
    const int quad = (lane >> 4) & 3;
    const int l16  = lane & 15;
    const int wm   = (wave >> 2) * 128;  // 2 M-waves
    const int wn   = (wave & 3) * 64;    // 4 N-waves

    const int flat = blockIdx.x + 4 * blockIdx.y;     // 0..127, xcd = flat%8
    const int t0   = (flat & 7) * 16 + (flat >> 3);   // bijective (128%8==0)
    const int m0   = (t0 >> 2) * 256;
    const int n0   = (t0 & 3) * 256;

    f32x4 acc[8][4];
#pragma unroll
    for (int i = 0; i < 8; i++)
#pragma unroll
        for (int j = 0; j < 4; j++) acc[i][j] = (f32x4)0.0f;

    // Issue one half-tile: seq s -> tile s>>2, kind s&3 (0,1=B-half, 2,3=A).
    // LDS linear dest; source 16B-group pre-swizzled: phys g holds global
    // group g ^ (row&7).
    auto issue = [&](int s) {
        if (s >= 64) return;
        const int tile = s >> 2;
        const int buf  = tile & 1;
        const int kind = s & 3;
        const int k0   = tile * 64;
        const int half = kind & 1;
        const bool isB = (kind < 2);
        const ushort* src = isB ? W : X;
        const int base    = isB ? n0 : m0;
        ushort* dst = smem + (isB ? 32768 : 0) + buf * 16384;
#pragma unroll
        for (int j = 0; j < 2; j++) {
            const int c   = half * 1024 + j * 512 + tid;  // chunk (lane-incl)
            const int row = c >> 3;
            const int gp  = (c & 7) ^ (row & 7);
            ASYNC16(&src[(size_t)(base + row) * 1024 + k0 + gp * 8],
                    dst + (size_t)(half * 1024 + j * 512 + wave * 64) * 8);
        }
    };

    // Prologue: tile0 (4 halves) + tile1 B0,B1 -> 12 loads; land tile0.
    for (int s = 0; s < 6; s++) issue(s);
    asm volatile("s_waitcnt vmcnt(4)" ::: "memory");
    __builtin_amdgcn_sched_barrier(0);
    __builtin_amdgcn_s_barrier();

    const int sw = l16 & 7;  // == row&7 at every read site below

    for (int t = 0; t < 16; t++) {
        const ushort* A  = smem + (t & 1) * 16384;
        const ushort* Bm = smem + 32768 + (t & 1) * 16384;
        bf16x8 bfrag[4][2];
#pragma unroll
        for (int p = 0; p < 4; p++) {
            issue(4 * t + p + 6);
            if (p == 0) {
#pragma unroll
                for (int nj = 0; nj < 4; nj++)
#pragma unroll
                    for (int ks = 0; ks < 2; ks++)
                        bfrag[nj][ks] = *(const bf16x8*)
                            &Bm[(size_t)(wn + nj * 16 + l16) * 64
                                + (((ks * 4 + quad) ^ sw) * 8)];
            }
            bf16x8 af[2][2];
#pragma unroll
            for (int i = 0; i < 2; i++)
#pragma unroll
                for (int ks = 0; ks < 2; ks++)
                    af[i][ks] = *(const bf16x8*)
                        &A[(size_t)(wm + (2 * p + i) * 16 + l16) * 64
                           + (((ks * 4 + quad) ^ sw) * 8)];
            __builtin_amdgcn_s_barrier();
            asm volatile("s_waitcnt lgkmcnt(0)" ::: "memory");
            __builtin_amdgcn_sched_barrier(0);
            __builtin_amdgcn_s_setprio(1);
#pragma unroll
            for (int i = 0; i < 2; i++)
#pragma unroll
                for (int nj = 0; nj < 4; nj++) {
                    acc[2 * p + i][nj] = MFMA32(af[i][0], bfrag[nj][0],
                                                acc[2 * p + i][nj]);
                    acc[2 * p + i][nj] = MFMA32(af[i][1], bfrag[nj][1],
                                                acc[2 * p + i][nj]);
                }
            __builtin_amdgcn_s_setprio(0);
            if (p == 3) {
                // all of tile t+1 landed; 2 halves (4 loads) stay in flight
                asm volatile("s_waitcnt vmcnt(4)" ::: "memory");
                __builtin_amdgcn_sched_barrier(0);
            }
            __builtin_amdgcn_s_barrier();
        }
    }

    // C/D: col = lane&15 (n), row = quad*4 + reg (m).
#pragma unroll
    for (int mi = 0; mi < 8; mi++) {
#pragma unroll
        for (int nj = 0; nj < 4; nj++) {
            const int n  = n0 + wn + nj * 16 + l16;
            const float bb = bias[n];
#pragma unroll
            for (int r = 0; r < 4; r++) {
                const int m = m0 + wm + mi * 16 + quad * 4 + r;
                const float val = (acc[mi][nj][r] + bb) * scale;
                if (mode == 2) {
                    ((float*)g.O[z])[(size_t)m * 1024 + n] = val;
                } else {
                    const int bat = m >> 11, s = m & 2047, h = n >> 6, d = n & 63;
                    ((ushort*)g.O[z])[((size_t)((bat * 16 + h) * 2048 + s)) * 64 + d]
                        = f2bf(val);
                }
            }
        }
    }
}

// ---------------------------------------------------------------------------
// Attention, P-in-registers (unchanged; ~97% combined pipe issue).
// ---------------------------------------------------------------------------
__global__ __launch_bounds__(256, 4) void attn(
    const ushort* __restrict__ Qp, const ushort* __restrict__ Kp,
    const ushort* __restrict__ Vp, ushort* __restrict__ ctx)
{
    __shared__ __attribute__((aligned(16))) ushort Ks[2][2 * 64 * 32];  // 2x8KB
    __shared__ __attribute__((aligned(16))) ushort Vs[2][64 * 64];      // 2x8KB

    const int tid  = threadIdx.x;
    const int lane = tid & 63;
    const int wave = tid >> 6;
    const int quad = lane >> 4;
    const int l16  = lane & 15;

    const int id = blockIdx.x;
    const int bh = (id & 7) * 8 + ((id >> 3) & 7);  // XCD-contiguous bh
    const int q0 = (id >> 6) * 128;
    const int b  = bh >> 4, h = bh & 15;

    const ushort* Qg = Qp + ((size_t)bh * 2048 + q0) * 64;
    const ushort* Kg = Kp + (size_t)bh * 2048 * 64;
    const ushort* Vg = Vp + (size_t)bh * 2048 * 64;

    // Loop-invariant Q fragments (B-operand: n=l16=query, k=quad*8+e).
    bf16x8 aq[2][2];
#pragma unroll
    for (int st = 0; st < 2; st++)
#pragma unroll
        for (int kk = 0; kk < 2; kk++)
            aq[st][kk] = *(const bf16x8*)&Qg[(size_t)(wave * 32 + st * 16 + l16) * 64
                                            + kk * 32 + quad * 8];

    f32x4 o[2][4];
#pragma unroll
    for (int st = 0; st < 2; st++)
#pragma unroll
        for (int jd = 0; jd < 4; jd++) o[st][jd] = (f32x4)0.0f;
#if HAVE_MFMA16K
    f32x4 ls[2] = {(f32x4)0.0f, (f32x4)0.0f};  // row sums, o-compatible layout
    union { uint u[2]; bf16x4 v; } ones;
    ones.u[0] = 0x3F803F80u; ones.u[1] = 0x3F803F80u;  // bf16 1.0 x4
#else
    float lsum[2] = {0.f, 0.f};
#endif

    // K tile: natural [half][row][32] layout. V tile: 4x16-subtiled V' via
    // source-swizzled async chunks; global src stays 128B-coalesced per 8 lanes.
    auto stage = [&](int buf, int n0) {
#pragma unroll
        for (int j = 0; j < 2; j++) {
            const int c    = j * 256 + tid;
            const int colq = c & 3;
            const int row  = (c >> 2) & 63;
            const int half = c >> 8;
            ASYNC16(&Kg[(size_t)(n0 + row) * 64 + half * 32 + colq * 8],
                    &Ks[buf][0] + (size_t)(j * 256 + wave * 64) * 8);
        }
#pragma unroll
        for (int j = 0; j < 2; j++) {
            const int c   = j * 256 + tid;
            const int key = ((c >> 5) << 2) | ((c >> 1) & 3);
            const int d   = (((c >> 3) & 3) << 4) | ((c & 1) << 3);
            ASYNC16(&Vg[(size_t)(n0 + key) * 64 + d],
                    &Vs[buf][0] + (size_t)(j * 256 + wave * 64) * 8);
        }
    };

    stage(0, 0);
    int cur = 0;

    for (int n0 = 0; n0 < 2048; n0 += 64) {
        __syncthreads();  // drains vmcnt: buf 'cur' is ready; prev reads done
        if (n0 + 64 < 2048) stage(cur ^ 1, n0 + 64);  // flies under compute

        // ---- S^T: 8 tiles (kb keys x st strips), exp2 + pack in-register ----
        uint pk[4][2][2];
#pragma unroll
        for (int kb = 0; kb < 4; kb++) {
            bf16x8 kf0 = *(const bf16x8*)&Ks[cur][(size_t)(kb * 16 + l16) * 32 + quad * 8];
            bf16x8 kf1 = *(const bf16x8*)&Ks[cur][(size_t)(64 + kb * 16 + l16) * 32 + quad * 8];
#pragma unroll
            for (int st = 0; st < 2; st++) {
                f32x4 s = (f32x4)0.0f;
                s = MFMA32(kf0, aq[st][0], s);
                s = MFMA32(kf1, aq[st][1], s);
                float e0 = __builtin_amdgcn_exp2f(s[0]);
                float e1 = __builtin_amdgcn_exp2f(s[1]);
                float e2 = __builtin_amdgcn_exp2f(s[2]);
                float e3 = __builtin_amdgcn_exp2f(s[3]);
                pk[kb][st][0] = cvtpk(e0, e1);
                pk[kb][st][1] = cvtpk(e2, e3);
#if !HAVE_MFMA16K
                lsum[st] += (e0 + e1) + (e2 + e3);
#endif
            }
        }

#if HAVE_MFMA16K
        // ---- PV: B-frags via hw transpose reads from subtiled V' ----
        const lds_ushort* vp = (const lds_ushort*)&Vs[cur][0] + quad * 256 + l16 * 4;
        bf16x4 vf[4][4];  // [jd][kb]
#define TRISSUE(JD)                                                            \
        TR16(vf[JD][0], vp, (JD) * 128 + 0);                                   \
        TR16(vf[JD][1], vp, (JD) * 128 + 2048);                                \
        TR16(vf[JD][2], vp, (JD) * 128 + 4096);                                \
        TR16(vf[JD][3], vp, (JD) * 128 + 6144);
        TRISSUE(0) TRISSUE(1) TRISSUE(2) TRISSUE(3)

        // Row-sum MFMAs (register-only) fill the tr-read latency window:
        // C[q][*] += sum_k P[q][k]; reg r holds query quad*4+r = o's layout.
#pragma unroll
        for (int kb = 0; kb < 4; kb++) {
#pragma unroll
            for (int st = 0; st < 2; st++) {
                union { uint u[2]; bf16x4 v; } pf;
                pf.u[0] = pk[kb][st][0];
                pf.u[1] = pk[kb][st][1];
                ls[st] = MFMA16K(pf.v, ones.v, ls[st]);
            }
        }

        // counted lgkmcnt: jd group ready when <=12-4*jd outstanding (FIFO,
        // trs are oldest). sched_barrier(0) after each wait (rule #18).
#define PVWAIT(N)                                                              \
        asm volatile("s_waitcnt lgkmcnt(" #N ")" ::: "memory");                \
        __builtin_amdgcn_sched_barrier(0);
#define PVJD(JD)                                                               \
        _Pragma("unroll")                                                      \
        for (int kb = 0; kb < 4; kb++) {                                       \
            _Pragma("unroll")                                                  \
            for (int st = 0; st < 2; st++) {                                   \
                union { uint u[2]; bf16x4 v; } pf;                             \
                pf.u[0] = pk[kb][st][0];                                       \
                pf.u[1] = pk[kb][st][1];                                       \
                o[st][JD] = MFMA16K(pf.v, vf[JD][kb], o[st][JD]);              \
            }                                                                  \
        }
        __builtin_amdgcn_s_setprio(1);
        PVWAIT(12) PVJD(0)
        PVWAIT(8)  PVJD(1)
        PVWAIT(4)  PVJD(2)
        PVWAIT(0)  PVJD(3)
        __builtin_amdgcn_s_setprio(0);
#else
        // Fallback: assemble K=32 A-frags via ds_bpermute, gather V from the
        // subtiled V' with scalar reads, PV with MFMA32. (Correctness path.)
        const int addr0 = 4 * ((2 * (quad & 1)) * 16 + l16);
        const int addr1 = addr0 + 64;
#pragma unroll
        for (int kt = 0; kt < 2; kt++) {
            bf16x8 apf[2];
#pragma unroll
            for (int st = 0; st < 2; st++) {
                union { uint u[4]; bf16x8 v; } t;
#pragma unroll
                for (int j = 0; j < 4; j++) {
                    uint src = (quad & 2) ? pk[kt * 2 + 1][st][j & 1]
                                          : pk[kt * 2][st][j & 1];
                    t.u[j] = (uint)__builtin_amdgcn_ds_bpermute(
                        (j >> 1) ? addr1 : addr0, (int)src);
                }
                apf[st] = t.v;
            }
#pragma unroll
            for (int jd = 0; jd < 4; jd++) {
                union { ushort s[8]; bf16x8 v; } vv;
#pragma unroll
                for (int e = 0; e < 8; e++) {
                    const int key = kt * 32 + quad * 8 + e;
                    const int d   = jd * 16 + l16;
                    vv.s[e] = Vs[cur][(key >> 2) * 256 + (d >> 4) * 64
                                      + (key & 3) * 16 + (d & 15)];
                }
#pragma unroll
                for (int st = 0; st < 2; st++)
                    o[st][jd] = MFMA32(apf[st], vv.v, o[st][jd]);
            }
        }
#endif
        cur ^= 1;
    }

#if HAVE_MFMA16K
    // ls[st][r] is already the row sum for query quad*4+r — no shuffles.
#pragma unroll
    for (int st = 0; st < 2; st++) {
        float inv[4];
#pragma unroll
        for (int r = 0; r < 4; r++) inv[r] = 1.0f / ls[st][r];
#pragma unroll
        for (int jd = 0; jd < 4; jd++) {
#pragma unroll
            for (int r = 0; r < 4; r++) {
                const int s = q0 + wave * 32 + st * 16 + quad * 4 + r;
                ctx[((size_t)(b * 2048 + s)) * 1024 + h * 64 + jd * 16 + l16] =
                    f2bf(o[st][jd][r] * inv[r]);
            }
        }
    }
#else
    // lsum holds per-(l16,quad) partials for query=l16: reduce over quads.
#pragma unroll
    for (int st = 0; st < 2; st++) {
        float lsv = lsum[st];
        lsv += __shfl_xor(lsv, 16, 64);
        lsv += __shfl_xor(lsv, 32, 64);
        float inv[4];
#pragma unroll
        for (int r = 0; r < 4; r++)
            inv[r] = 1.0f / __shfl(lsv, quad * 4 + r, 64);
#pragma unroll
        for (int jd = 0; jd < 4; jd++) {
#pragma unroll
            for (int r = 0; r < 4; r++) {
                const int s = q0 + wave * 32 + st * 16 + quad * 4 + r;
                ctx[((size_t)(b * 2048 + s)) * 1024 + h * 64 + jd * 16 + l16] =
                    f2bf(o[st][jd][r] * inv[r]);
            }
        }
    }
#endif
}

extern "C" void kernel_launch(void* const* d_in, const int* in_sizes, int n_in,
                              void* d_out, int out_size, void* d_ws, size_t ws_size,
                              hipStream_t stream) {
    const float* q    = (const float*)d_in[0];
    const float* k    = (const float*)d_in[1];
    const float* v    = (const float*)d_in[2];
    const float* wq_w = (const float*)d_in[3];
    const float* wq_b = (const float*)d_in[4];
    const float* wk_w = (const float*)d_in[5];
    const float* wk_b = (const float*)d_in[6];
    const float* wv_w = (const float*)d_in[7];
    const float* wv_b = (const float*)d_in[8];
    const float* wo_w = (const float*)d_in[9];
    const float* wo_b = (const float*)d_in[10];
    float* out = (float*)d_out;

    const size_t NE = (size_t)4 * 2048 * 1024;
    const size_t NW = (size_t)1024 * 1024;
    const size_t need_fused = (6 * NE + 4 * NW) * 2;
    const size_t LDSB = 131072;  // 128KB dynamic LDS for gemm256

    dim3 blk(256);
    dim3 gblk(512);
    dim3 ggrid(4, 32, 3);   // 128 wgs/z: 32 m-tiles x 4 n-tiles
    dim3 ggrid1(4, 32, 1);

    if (ws_size >= need_fused) {
        ushort* Xq = (ushort*)d_ws;
        ushort* Xk = Xq + NE;
        ushort* Xv = Xk + NE;
        ushort* Wq = Xv + NE;
        ushort* Wk = Wq + NW;
        ushort* Wv = Wk + NW;
        ushort* Wo = Wv + NW;
        ushort* Qp = Wo + NW;
        ushort* Kp = Qp + NE;
        ushort* Vp = Kp + NE;
        ushort* ctx = Xq;

        CvtArgs ca;
        ca.s[0]=q;    ca.d[0]=Xq; ca.nb[0]=4096;
        ca.s[1]=k;    ca.d[1]=Xk; ca.nb[1]=4096;
        ca.s[2]=v;    ca.d[2]=Xv; ca.nb[2]=4096;
        ca.s[3]=wq_w; ca.d[3]=Wq; ca.nb[3]=512;
        ca.s[4]=wk_w; ca.d[4]=Wk; ca.nb[4]=512;
        ca.s[5]=wv_w; ca.d[5]=Wv; ca.nb[5]=512;
        ca.s[6]=wo_w; ca.d[6]=Wo; ca.nb[6]=512;
        cvtk<<<dim3(4096, 7), blk, 0, stream>>>(ca);

        GemmArgs ga;
        ga.X[0]=Xq; ga.W[0]=Wq; ga.B[0]=wq_b; ga.O[0]=Qp; ga.mode[0]=0; ga.scale[0]=QSCALE;
        ga.X[1]=Xk; ga.W[1]=Wk; ga.B[1]=wk_b; ga.O[1]=Kp; ga.mode[1]=0; ga.scale[1]=1.0f;
        ga.X[2]=Xv; ga.W[2]=Wv; ga.B[2]=wv_b; ga.O[2]=Vp; ga.mode[2]=0; ga.scale[2]=1.0f;
        gemm256<<<ggrid, gblk, LDSB, stream>>>(ga);

        attn<<<dim3(1024), blk, 0, stream>>>(Qp, Kp, Vp, ctx);

        GemmArgs go;
        for (int i = 0; i < 3; i++) {
            go.X[i]=ctx; go.W[i]=Wo; go.B[i]=wo_b;
            go.O[i]=out; go.mode[i]=2; go.scale[i]=1.0f;
        }
        gemm256<<<ggrid1, gblk, LDSB, stream>>>(go);
    } else {
        // Serial fallback: Xb reused per projection, then as ctx (68 MB).
        ushort* Xb  = (ushort*)d_ws;
        ushort* Wb  = Xb + NE;
        ushort* Wob = Wb + NW;
        ushort* Qp  = Wob + NW;
        ushort* Kp  = Qp + NE;
        ushort* Vp  = Kp + NE;
        ushort* ctx = Xb;

        const float* xs[3] = {q, k, v};
        const float* ws[3] = {wq_w, wk_w, wv_w};
        const float* bs[3] = {wq_b, wk_b, wv_b};
        ushort* os[3] = {Qp, Kp, Vp};
        for (int p = 0; p < 3; p++) {
            CvtArgs c;
            c.s[0]=xs[p]; c.d[0]=Xb; c.nb[0]=4096;
            c.s[1]=ws[p]; c.d[1]=Wb; c.nb[1]=512;
            for (int i = 2; i < 7; i++) { c.s[i]=xs[p]; c.d[i]=Xb; c.nb[i]=0; }
            cvtk<<<dim3(4096, 2), blk, 0, stream>>>(c);
            GemmArgs gg;
            for (int i = 0; i < 3; i++) {
                gg.X[i]=Xb; gg.W[i]=Wb; gg.B[i]=bs[p]; gg.O[i]=os[p];
                gg.mode[i]=0; gg.scale[i]=(p == 0) ? QSCALE : 1.0f;
            }
            gemm256<<<ggrid1, gblk, LDSB, stream>>>(gg);
        }

        attn<<<dim3(1024), blk, 0, stream>>>(Qp, Kp, Vp, ctx);

        CvtArgs c;
        c.s[0]=wo_w; c.d[0]=Wob; c.nb[0]=512;
        for (int i = 1; i < 7; i++) { c.s[i]=wo_w; c.d[i]=Wob; c.nb[i]=0; }
        cvtk<<<dim3(512, 1), blk, 0, stream>>>(c);
        GemmArgs go;
        for (int i = 0; i < 3; i++) {
            go.X[i]=ctx; go.W[i]=Wob; go.B[i]=wo_b;
            go.O[i]=out; go.mode[i]=2; go.scale[i]=1.0f;
        }
        gemm256<<<ggrid1, gblk, LDSB, stream>>>(go);
    }
}

// Round 9
// 335.732 us; speedup vs baseline: 1.1685x; 1.0278x over previous
//
#include <hip/hip_runtime.h>
#include <hip/hip_bf16.h>

typedef __attribute__((ext_vector_type(8))) short bf16x8;
typedef __attribute__((ext_vector_type(4))) short bf16x4;
typedef __attribute__((ext_vector_type(4))) float f32x4;
typedef __attribute__((address_space(3))) ushort lds_ushort;

#define MFMA32(a, b, c) __builtin_amdgcn_mfma_f32_16x16x32_bf16(a, b, c, 0, 0, 0)
#if __has_builtin(__builtin_amdgcn_mfma_f32_16x16x16bf16_1k)
#define HAVE_MFMA16K 1
#define MFMA16K(a, b, c) __builtin_amdgcn_mfma_f32_16x16x16bf16_1k(a, b, c, 0, 0, 0)
#else
#define HAVE_MFMA16K 0
#endif

// async global->LDS, 16B/lane; LDS dest = wave-uniform base + lane*16.
#define ASYNC16(g, l)                                                          \
    __builtin_amdgcn_global_load_lds(                                          \
        (const __attribute__((address_space(1))) unsigned int*)(g),            \
        (__attribute__((address_space(3))) unsigned int*)(l), 16, 0, 0)

// hw transpose read: per 16-lane group reads 128B window as 4x16 bf16
// row-major, lane l gets column (l&15). addr = window_base + (l&15)*8 bytes.
#define TR16(dst, addr, OFF)                                                   \
    asm volatile("ds_read_b64_tr_b16 %0, %1 offset:%2"                         \
                 : "=v"(dst) : "v"(addr), "i"(OFF))

__device__ __forceinline__ ushort f2bf(float f) {
    __hip_bfloat16 h = __float2bfloat16(f);  // RNE
    return *reinterpret_cast<ushort*>(&h);
}
// pack two f32 to bf16 pair in one instruction (T12; no builtin on gfx950).
__device__ __forceinline__ uint cvtpk(float a, float b) {
    uint r;
    asm("v_cvt_pk_bf16_f32 %0, %1, %2" : "=v"(r) : "v"(a), "v"(b));
    return r;
}

// log2(e)/sqrt(64), folded into Q projection -> attn does exp2(score) raw.
#define QSCALE 0.18033688011112042f

// ---------------------------------------------------------------------------
// fp32 -> bf16 convert, multi-range (q,k,v + 4 weights).
// ---------------------------------------------------------------------------
struct CvtArgs { const float* s[7]; ushort* d[7]; int nb[7]; };

__global__ __launch_bounds__(256) void cvtk(CvtArgs a) {
    const int z = blockIdx.y;
    if ((int)blockIdx.x >= a.nb[z]) return;
    const float* s = a.s[z];
    ushort* d = a.d[z];
    const size_t i = (size_t)blockIdx.x * 2048 + threadIdx.x * 8;
    float4 f0 = *(const float4*)&s[i];
    float4 f1 = *(const float4*)&s[i + 4];
    *(ushort4*)&d[i]     = make_ushort4(f2bf(f0.x), f2bf(f0.y), f2bf(f0.z), f2bf(f0.w));
    *(ushort4*)&d[i + 4] = make_ushort4(f2bf(f1.x), f2bf(f1.y), f2bf(f1.z), f2bf(f1.w));
}

// ---------------------------------------------------------------------------
// 256x128 counted-vmcnt bf16 NT GEMM (R7 version, under bisection test):
// out = (X@W^T + bias) * scale
//   mode 0: bf16 out [B=4,H=16,S=2048,64]; mode 2: fp32 out [8192,1024].
// BM=256, BN=128, BK=64, 512 thr (8 waves 2Mx4N), per-wave 128x32 = acc[8][2].
// vmcnt ledger: entering tile t, 2 loads in flight (t+1's B0,B1); tile t
// issues A0(2)+A1(2)+B0(1)+B1(1) -> 8 at p3 -> vmcnt(2) retires all of t+1;
// t>=14: issue stream exhausted -> full drain vmcnt(0).
// Bank swizzle: phys 16B-group = logical ^ (row&7) on DMA source and reads.
// ---------------------------------------------------------------------------
struct GemmArgs {
    const ushort* X[3]; const ushort* W[3]; const float* B[3];
    void* O[3]; int mode[3]; float scale[3];
};

__global__ __launch_bounds__(512, 2) void gemmk(GemmArgs g) {
    extern __shared__ __attribute__((aligned(16))) ushort smem[];
    // A: [0, 32768) ushorts (2 bufs x 16384); B: [32768, 49152) (2 x 8192).

    const int z = blockIdx.z;
    const ushort* __restrict__ X = g.X[z];
    const ushort* __restrict__ W = g.W[z];
    const float*  __restrict__ bias = g.B[z];
    const int mode = g.mode[z];
    const float scale = g.scale[z];

    const int tid  = threadIdx.x;
    const int lane = tid & 63;
    const int wave = tid >> 6;
    const int quad = (lane >> 4) & 3;
    const int l16  = lane & 15;
    const int wm   = (wave >> 2) * 128;  // 2 M-waves: 128 rows each
    const int wn   = (wave & 3) * 32;    // 4 N-waves: 32 cols each

    const int flat = blockIdx.x + 8 * blockIdx.y;     // 0..255, xcd = flat%8
    const int t0   = (flat & 7) * 32 + (flat >> 3);   // bijective (256%8==0)
    const int m0   = (t0 >> 3) * 256;
    const int n0   = (t0 & 7) * 128;

    f32x4 acc[8][2];
#pragma unroll
    for (int i = 0; i < 8; i++)
#pragma unroll
        for (int j = 0; j < 2; j++) acc[i][j] = (f32x4)0.0f;

    // seq s -> tile s>>2, kind s&3 (0,1 = B half, 2,3 = A half).
    auto issue = [&](int s) {
        if (s >= 64) return;
        const int tile = s >> 2;
        const int buf  = tile & 1;
        const int kind = s & 3;
        const int k0   = tile * 64;
        if (kind < 2) {
            // B half: 64 rows x 64k = 8KB -> 1 ASYNC16/thread.
            const int row = tid >> 3;
            const int gp  = (tid & 7) ^ (row & 7);
            ASYNC16(&W[(size_t)(n0 + kind * 64 + row) * 1024 + k0 + gp * 8],
                    smem + 32768 + buf * 8192 + kind * 4096 + wave * 512);
        } else {
            // A half: 128 rows x 64k = 16KB -> 2 ASYNC16/thread.
            const int half = kind - 2;
#pragma unroll
            for (int j = 0; j < 2; j++) {
                const int c   = j * 512 + tid;
                const int row = c >> 3;
                const int gp  = (c & 7) ^ (row & 7);
                ASYNC16(&X[(size_t)(m0 + half * 128 + row) * 1024 + k0 + gp * 8],
                        smem + buf * 16384 + half * 8192 + j * 4096 + wave * 512);
            }
        }
    };

    // Prologue: tile0 (6 loads) + tile1 B0,B1 (2 loads); land tile0.
    for (int s = 0; s < 6; s++) issue(s);
    asm volatile("s_waitcnt vmcnt(2)" ::: "memory");
    __builtin_amdgcn_sched_barrier(0);
    __builtin_amdgcn_s_barrier();

    const int sw = l16 & 7;

    for (int t = 0; t < 16; t++) {
        const ushort* A  = smem + (t & 1) * 16384;
        const ushort* Bm = smem + 32768 + (t & 1) * 8192;
        bf16x8 bfrag[2][2];
#pragma unroll
        for (int p = 0; p < 4; p++) {
            issue(4 * t + p + 6);
            if (p == 0) {
#pragma unroll
                for (int nj = 0; nj < 2; nj++)
#pragma unroll
                    for (int ks = 0; ks < 2; ks++) {
                        const int br = wn + nj * 16 + l16;
                        bfrag[nj][ks] = *(const bf16x8*)
                            &Bm[(size_t)(br >> 6) * 4096 + (br & 63) * 64
                                + (((ks * 4 + quad) ^ sw) * 8)];
                    }
            }
            bf16x8 af[2][2];
#pragma unroll
            for (int i = 0; i < 2; i++)
#pragma unroll
                for (int ks = 0; ks < 2; ks++) {
                    const int ar = wm + (2 * p + i) * 16 + l16;
                    af[i][ks] = *(const bf16x8*)
                        &A[(size_t)(ar >> 7) * 8192 + (ar & 127) * 64
                           + (((ks * 4 + quad) ^ sw) * 8)];
                }
            __builtin_amdgcn_s_barrier();
            asm volatile("s_waitcnt lgkmcnt(0)" ::: "memory");
            __builtin_amdgcn_sched_barrier(0);
            __builtin_amdgcn_s_setprio(1);
#pragma unroll
            for (int i = 0; i < 2; i++)
#pragma unroll
                for (int nj = 0; nj < 2; nj++) {
                    acc[2 * p + i][nj] = MFMA32(af[i][0], bfrag[nj][0],
                                                acc[2 * p + i][nj]);
                    acc[2 * p + i][nj] = MFMA32(af[i][1], bfrag[nj][1],
                                                acc[2 * p + i][nj]);
                }
            __builtin_amdgcn_s_setprio(0);
            if (p == 3) {
                if (t < 14) {
                    // tile t+1 fully landed; t+2's B0,B1 stay in flight.
                    asm volatile("s_waitcnt vmcnt(2)" ::: "memory");
                } else {
                    // issue stream exhausted: full drain (R7 fix).
                    asm volatile("s_waitcnt vmcnt(0)" ::: "memory");
                }
                __builtin_amdgcn_sched_barrier(0);
            }
            __builtin_amdgcn_s_barrier();
        }
    }

    // C/D: col = lane&15 (n), row = quad*4 + reg (m).
#pragma unroll
    for (int mi = 0; mi < 8; mi++) {
#pragma unroll
        for (int nj = 0; nj < 2; nj++) {
            const int n  = n0 + wn + nj * 16 + l16;
            const float bb = bias[n];
#pragma unroll
            for (int r = 0; r < 4; r++) {
                const int m = m0 + wm + mi * 16 + quad * 4 + r;
                const float val = (acc[mi][nj][r] + bb) * scale;
                if (mode == 2) {
                    ((float*)g.O[z])[(size_t)m * 1024 + n] = val;
                } else {
                    const int bat = m >> 11, s = m & 2047, h = n >> 6, d = n & 63;
                    ((ushort*)g.O[z])[((size_t)((bat * 16 + h) * 2048 + s)) * 64 + d]
                        = f2bf(val);
                }
            }
        }
    }
}

// ---------------------------------------------------------------------------
// Attention — VERBATIM R5 version (known-good: passed R2/R3(base)/R5 at
// ~90 us). st=2, wave owns 32 q-rows, grid 1024, 4 blocks/CU.
// ---------------------------------------------------------------------------
__global__ __launch_bounds__(256, 4) void attn(
    const ushort* __restrict__ Qp, const ushort* __restrict__ Kp,
    const ushort* __restrict__ Vp, ushort* __restrict__ ctx)
{
    __shared__ __attribute__((aligned(16))) ushort Ks[2][2 * 64 * 32];  // 2x8KB
    __shared__ __attribute__((aligned(16))) ushort Vs[2][64 * 64];      // 2x8KB

    const int tid  = threadIdx.x;
    const int lane = tid & 63;
    const int wave = tid >> 6;
    const int quad = lane >> 4;
    const int l16  = lane & 15;

    const int id = blockIdx.x;
    const int bh = (id & 7) * 8 + ((id >> 3) & 7);  // XCD-contiguous bh
    const int q0 = (id >> 6) * 128;
    const int b  = bh >> 4, h = bh & 15;

    const ushort* Qg = Qp + ((size_t)bh * 2048 + q0) * 64;
    const ushort* Kg = Kp + (size_t)bh * 2048 * 64;
    const ushort* Vg = Vp + (size_t)bh * 2048 * 64;

    // Loop-invariant Q fragments (B-operand: n=l16=query, k=quad*8+e).
    bf16x8 aq[2][2];
#pragma unroll
    for (int st = 0; st < 2; st++)
#pragma unroll
        for (int kk = 0; kk < 2; kk++)
            aq[st][kk] = *(const bf16x8*)&Qg[(size_t)(wave * 32 + st * 16 + l16) * 64
                                            + kk * 32 + quad * 8];

    f32x4 o[2][4];
#pragma unroll
    for (int st = 0; st < 2; st++)
#pragma unroll
        for (int jd = 0; jd < 4; jd++) o[st][jd] = (f32x4)0.0f;
#if HAVE_MFMA16K
    f32x4 ls[2] = {(f32x4)0.0f, (f32x4)0.0f};  // row sums, o-compatible layout
    union { uint u[2]; bf16x4 v; } ones;
    ones.u[0] = 0x3F803F80u; ones.u[1] = 0x3F803F80u;  // bf16 1.0 x4
#else
    float lsum[2] = {0.f, 0.f};
#endif

    // K tile: natural [half][row][32] layout. V tile: 4x16-subtiled V' via
    // source-swizzled async chunks; global src stays 128B-coalesced per 8 lanes.
    auto stage = [&](int buf, int n0) {
#pragma unroll
        for (int j = 0; j < 2; j++) {
            const int c    = j * 256 + tid;
            const int colq = c & 3;
            const int row  = (c >> 2) & 63;
            const int half = c >> 8;
            ASYNC16(&Kg[(size_t)(n0 + row) * 64 + half * 32 + colq * 8],
                    &Ks[buf][0] + (size_t)(j * 256 + wave * 64) * 8);
        }
#pragma unroll
        for (int j = 0; j < 2; j++) {
            const int c   = j * 256 + tid;
            const int key = ((c >> 5) << 2) | ((c >> 1) & 3);
            const int d   = (((c >> 3) & 3) << 4) | ((c & 1) << 3);
            ASYNC16(&Vg[(size_t)(n0 + key) * 64 + d],
                    &Vs[buf][0] + (size_t)(j * 256 + wave * 64) * 8);
        }
    };

    stage(0, 0);
    int cur = 0;

    for (int n0 = 0; n0 < 2048; n0 += 64) {
        __syncthreads();  // drains vmcnt: buf 'cur' is ready; prev reads done
        if (n0 + 64 < 2048) stage(cur ^ 1, n0 + 64);  // flies under compute

        // ---- S^T: 8 tiles (kb keys x st strips), exp2 + pack in-register ----
        uint pk[4][2][2];
#pragma unroll
        for (int kb = 0; kb < 4; kb++) {
            bf16x8 kf0 = *(const bf16x8*)&Ks[cur][(size_t)(kb * 16 + l16) * 32 + quad * 8];
            bf16x8 kf1 = *(const bf16x8*)&Ks[cur][(size_t)(64 + kb * 16 + l16) * 32 + quad * 8];
#pragma unroll
            for (int st = 0; st < 2; st++) {
                f32x4 s = (f32x4)0.0f;
                s = MFMA32(kf0, aq[st][0], s);
                s = MFMA32(kf1, aq[st][1], s);
                float e0 = __builtin_amdgcn_exp2f(s[0]);
                float e1 = __builtin_amdgcn_exp2f(s[1]);
                float e2 = __builtin_amdgcn_exp2f(s[2]);
                float e3 = __builtin_amdgcn_exp2f(s[3]);
                pk[kb][st][0] = cvtpk(e0, e1);
                pk[kb][st][1] = cvtpk(e2, e3);
#if !HAVE_MFMA16K
                lsum[st] += (e0 + e1) + (e2 + e3);
#endif
            }
        }

#if HAVE_MFMA16K
        // ---- PV: B-frags via hw transpose reads from subtiled V' ----
        const lds_ushort* vp = (const lds_ushort*)&Vs[cur][0] + quad * 256 + l16 * 4;
        bf16x4 vf[4][4];  // [jd][kb]
#define TRISSUE(JD)                                                            \
        TR16(vf[JD][0], vp, (JD) * 128 + 0);                                   \
        TR16(vf[JD][1], vp, (JD) * 128 + 2048);                                \
        TR16(vf[JD][2], vp, (JD) * 128 + 4096);                                \
        TR16(vf[JD][3], vp, (JD) * 128 + 6144);
        TRISSUE(0) TRISSUE(1) TRISSUE(2) TRISSUE(3)

        // Row-sum MFMAs (register-only) fill the tr-read latency window.
#pragma unroll
        for (int kb = 0; kb < 4; kb++) {
#pragma unroll
            for (int st = 0; st < 2; st++) {
                union { uint u[2]; bf16x4 v; } pf;
                pf.u[0] = pk[kb][st][0];
                pf.u[1] = pk[kb][st][1];
                ls[st] = MFMA16K(pf.v, ones.v, ls[st]);
            }
        }

        // counted lgkmcnt: jd group ready when <=12-4*jd outstanding (FIFO,
        // trs are oldest). sched_barrier(0) after each wait (rule #18).
#define PVWAIT(N)                                                              \
        asm volatile("s_waitcnt lgkmcnt(" #N ")" ::: "memory");                \
        __builtin_amdgcn_sched_barrier(0);
#define PVJD(JD)                                                               \
        _Pragma("unroll")                                                      \
        for (int kb = 0; kb < 4; kb++) {                                       \
            _Pragma("unroll")                                                  \
            for (int st = 0; st < 2; st++) {                                   \
                union { uint u[2]; bf16x4 v; } pf;                             \
                pf.u[0] = pk[kb][st][0];                                       \
                pf.u[1] = pk[kb][st][1];                                       \
                o[st][JD] = MFMA16K(pf.v, vf[JD][kb], o[st][JD]);              \
            }                                                                  \
        }
        __builtin_amdgcn_s_setprio(1);
        PVWAIT(12) PVJD(0)
        PVWAIT(8)  PVJD(1)
        PVWAIT(4)  PVJD(2)
        PVWAIT(0)  PVJD(3)
        __builtin_amdgcn_s_setprio(0);
#else
        // Fallback: assemble K=32 A-frags via ds_bpermute, gather V from the
        // subtiled V' with scalar reads, PV with MFMA32. (Correctness path.)
        const int addr0 = 4 * ((2 * (quad & 1)) * 16 + l16);
        const int addr1 = addr0 + 64;
#pragma unroll
        for (int kt = 0; kt < 2; kt++) {
            bf16x8 apf[2];
#pragma unroll
            for (int st = 0; st < 2; st++) {
                union { uint u[4]; bf16x8 v; } t;
#pragma unroll
                for (int j = 0; j < 4; j++) {
                    uint src = (quad & 2) ? pk[kt * 2 + 1][st][j & 1]
                                          : pk[kt * 2][st][j & 1];
                    t.u[j] = (uint)__builtin_amdgcn_ds_bpermute(
                        (j >> 1) ? addr1 : addr0, (int)src);
                }
                apf[st] = t.v;
            }
#pragma unroll
            for (int jd = 0; jd < 4; jd++) {
                union { ushort s[8]; bf16x8 v; } vv;
#pragma unroll
                for (int e = 0; e < 8; e++) {
                    const int key = kt * 32 + quad * 8 + e;
                    const int d   = jd * 16 + l16;
                    vv.s[e] = Vs[cur][(key >> 2) * 256 + (d >> 4) * 64
                                      + (key & 3) * 16 + (d & 15)];
                }
#pragma unroll
                for (int st = 0; st < 2; st++)
                    o[st][jd] = MFMA32(apf[st], vv.v, o[st][jd]);
            }
        }
#endif
        cur ^= 1;
    }

#if HAVE_MFMA16K
    // ls[st][r] is already the row sum for query quad*4+r — no shuffles.
#pragma unroll
    for (int st = 0; st < 2; st++) {
        float inv[4];
#pragma unroll
        for (int r = 0; r < 4; r++) inv[r] = 1.0f / ls[st][r];
#pragma unroll
        for (int jd = 0; jd < 4; jd++) {
#pragma unroll
            for (int r = 0; r < 4; r++) {
                const int s = q0 + wave * 32 + st * 16 + quad * 4 + r;
                ctx[((size_t)(b * 2048 + s)) * 1024 + h * 64 + jd * 16 + l16] =
                    f2bf(o[st][jd][r] * inv[r]);
            }
        }
    }
#else
    // lsum holds per-(l16,quad) partials for query=l16: reduce over quads.
#pragma unroll
    for (int st = 0; st < 2; st++) {
        float lsv = lsum[st];
        lsv += __shfl_xor(lsv, 16, 64);
        lsv += __shfl_xor(lsv, 32, 64);
        float inv[4];
#pragma unroll
        for (int r = 0; r < 4; r++)
            inv[r] = 1.0f / __shfl(lsv, quad * 4 + r, 64);
#pragma unroll
        for (int jd = 0; jd < 4; jd++) {
#pragma unroll
            for (int r = 0; r < 4; r++) {
                const int s = q0 + wave * 32 + st * 16 + quad * 4 + r;
                ctx[((size_t)(b * 2048 + s)) * 1024 + h * 64 + jd * 16 + l16] =
                    f2bf(o[st][jd][r] * inv[r]);
            }
        }
    }
#endif
}

extern "C" void kernel_launch(void* const* d_in, const int* in_sizes, int n_in,
                              void* d_out, int out_size, void* d_ws, size_t ws_size,
                              hipStream_t stream) {
    const float* q    = (const float*)d_in[0];
    const float* k    = (const float*)d_in[1];
    const float* v    = (const float*)d_in[2];
    const float* wq_w = (const float*)d_in[3];
    const float* wq_b = (const float*)d_in[4];
    const float* wk_w = (const float*)d_in[5];
    const float* wk_b = (const float*)d_in[6];
    const float* wv_w = (const float*)d_in[7];
    const float* wv_b = (const float*)d_in[8];
    const float* wo_w = (const float*)d_in[9];
    const float* wo_b = (const float*)d_in[10];
    float* out = (float*)d_out;

    const size_t NE = (size_t)4 * 2048 * 1024;
    const size_t NW = (size_t)1024 * 1024;
    const size_t need_fused = (6 * NE + 4 * NW) * 2;
    const size_t LDSB = 98304;  // 96KB dynamic LDS for gemmk

    dim3 blk(256);
    dim3 gblk(512);
    dim3 ggrid(8, 32, 3);   // 256 wgs/z: 32 m-tiles x 8 n-tiles
    dim3 ggrid1(8, 32, 1);

    if (ws_size >= need_fused) {
        ushort* Xq = (ushort*)d_ws;
        ushort* Xk = Xq + NE;
        ushort* Xv = Xk + NE;
        ushort* Wq = Xv + NE;
        ushort* Wk = Wq + NW;
        ushort* Wv = Wk + NW;
        ushort* Wo = Wv + NW;
        ushort* Qp = Wo + NW;
        ushort* Kp = Qp + NE;
        ushort* Vp = Kp + NE;
        ushort* ctx = Xq;

        CvtArgs ca;
        ca.s[0]=q;    ca.d[0]=Xq; ca.nb[0]=4096;
        ca.s[1]=k;    ca.d[1]=Xk; ca.nb[1]=4096;
        ca.s[2]=v;    ca.d[2]=Xv; ca.nb[2]=4096;
        ca.s[3]=wq_w; ca.d[3]=Wq; ca.nb[3]=512;
        ca.s[4]=wk_w; ca.d[4]=Wk; ca.nb[4]=512;
        ca.s[5]=wv_w; ca.d[5]=Wv; ca.nb[5]=512;
        ca.s[6]=wo_w; ca.d[6]=Wo; ca.nb[6]=512;
        cvtk<<<dim3(4096, 7), blk, 0, stream>>>(ca);

        GemmArgs ga;
        ga.X[0]=Xq; ga.W[0]=Wq; ga.B[0]=wq_b; ga.O[0]=Qp; ga.mode[0]=0; ga.scale[0]=QSCALE;
        ga.X[1]=Xk; ga.W[1]=Wk; ga.B[1]=wk_b; ga.O[1]=Kp; ga.mode[1]=0; ga.scale[1]=1.0f;
        ga.X[2]=Xv; ga.W[2]=Wv; ga.B[2]=wv_b; ga.O[2]=Vp; ga.mode[2]=0; ga.scale[2]=1.0f;
        gemmk<<<ggrid, gblk, LDSB, stream>>>(ga);

        attn<<<dim3(1024), blk, 0, stream>>>(Qp, Kp, Vp, ctx);

        GemmArgs go;
        for (int i = 0; i < 3; i++) {
            go.X[i]=ctx; go.W[i]=Wo; go.B[i]=wo_b;
            go.O[i]=out; go.mode[i]=2; go.scale[i]=1.0f;
        }
        gemmk<<<ggrid1, gblk, LDSB, stream>>>(go);
    } else {
        // Serial fallback: Xb reused per projection, then as ctx (68 MB).
        ushort* Xb  = (ushort*)d_ws;
        ushort* Wb  = Xb + NE;
        ushort* Wob = Wb + NW;
        ushort* Qp  = Wob + NW;
        ushort* Kp  = Qp + NE;
        ushort* Vp  = Kp + NE;
        ushort* ctx = Xb;

        const float* xs[3] = {q, k, v};
        const float* ws[3] = {wq_w, wk_w, wv_w};
        const float* bs[3] = {wq_b, wk_b, wv_b};
        ushort* os[3] = {Qp, Kp, Vp};
        for (int p = 0; p < 3; p++) {
            CvtArgs c;
            c.s[0]=xs[p]; c.d[0]=Xb; c.nb[0]=4096;
            c.s[1]=ws[p]; c.d[1]=Wb; c.nb[1]=512;
            for (int i = 2; i < 7; i++) { c.s[i]=xs[p]; c.d[i]=Xb; c.nb[i]=0; }
            cvtk<<<dim3(4096, 2), blk, 0, stream>>>(c);
            GemmArgs gg;
            for (int i = 0; i < 3; i++) {
                gg.X[i]=Xb; gg.W[i]=Wb; gg.B[i]=bs[p]; gg.O[i]=os[p];
                gg.mode[i]=0; gg.scale[i]=(p == 0) ? QSCALE : 1.0f;
            }
            gemmk<<<ggrid1, gblk, LDSB, stream>>>(gg);
        }

        attn<<<dim3(1024), blk, 0, stream>>>(Qp, Kp, Vp, ctx);

        CvtArgs c;
        c.s[0]=wo_w; c.d[0]=Wob; c.nb[0]=512;
        for (int i = 1; i < 7; i++) { c.s[i]=wo_w; c.d[i]=Wob; c.nb[i]=0; }
        cvtk<<<dim3(512, 1), blk, 0, stream>>>(c);
        GemmArgs go;
        for (int i = 0; i < 3; i++) {
            go.X[i]=ctx; go.W[i]=Wob; go.B[i]=wo_b;
            go.O[i]=out; go.mode[i]=2; go.scale[i]=1.0f;
        }
        gemmk<<<ggrid1, gblk, LDSB, stream>>>(go);
    }
}

// Round 11
// 326.178 us; speedup vs baseline: 1.2027x; 1.0293x over previous
//
#include <hip/hip_runtime.h>
#include <hip/hip_bf16.h>

typedef __attribute__((ext_vector_type(8))) short bf16x8;
typedef __attribute__((ext_vector_type(4))) short bf16x4;
typedef __attribute__((ext_vector_type(4))) float f32x4;
typedef __attribute__((address_space(3))) ushort lds_ushort;

#define MFMA32(a, b, c) __builtin_amdgcn_mfma_f32_16x16x32_bf16(a, b, c, 0, 0, 0)
#if __has_builtin(__builtin_amdgcn_mfma_f32_16x16x16bf16_1k)
#define HAVE_MFMA16K 1
#define MFMA16K(a, b, c) __builtin_amdgcn_mfma_f32_16x16x16bf16_1k(a, b, c, 0, 0, 0)
#else
#define HAVE_MFMA16K 0
#endif

// async global->LDS, 16B/lane; LDS dest = wave-uniform base + lane*16.
#define ASYNC16(g, l)                                                          \
    __builtin_amdgcn_global_load_lds(                                          \
        (const __attribute__((address_space(1))) unsigned int*)(g),            \
        (__attribute__((address_space(3))) unsigned int*)(l), 16, 0, 0)

// hw transpose read: per 16-lane group reads 128B window as 4x16 bf16
// row-major, lane l gets column (l&15). addr = window_base + (l&15)*8 bytes.
#define TR16(dst, addr, OFF)                                                   \
    asm volatile("ds_read_b64_tr_b16 %0, %1 offset:%2"                         \
                 : "=v"(dst) : "v"(addr), "i"(OFF))

__device__ __forceinline__ ushort f2bf(float f) {
    __hip_bfloat16 h = __float2bfloat16(f);  // RNE
    return *reinterpret_cast<ushort*>(&h);
}
// pack two f32 to bf16 pair in one instruction (T12; no builtin on gfx950).
__device__ __forceinline__ uint cvtpk(float a, float b) {
    uint r;
    asm("v_cvt_pk_bf16_f32 %0, %1, %2" : "=v"(r) : "v"(a), "v"(b));
    return r;
}

// log2(e)/sqrt(64), folded into Q projection -> attn does exp2(score) raw.
#define QSCALE 0.18033688011112042f

// ---------------------------------------------------------------------------
// fp32 -> bf16 convert, multi-range (q,k,v + 4 weights).
// ---------------------------------------------------------------------------
struct CvtArgs { const float* s[7]; ushort* d[7]; int nb[7]; };

__global__ __launch_bounds__(256) void cvtk(CvtArgs a) {
    const int z = blockIdx.y;
    if ((int)blockIdx.x >= a.nb[z]) return;
    const float* s = a.s[z];
    ushort* d = a.d[z];
    const size_t i = (size_t)blockIdx.x * 2048 + threadIdx.x * 8;
    float4 f0 = *(const float4*)&s[i];
    float4 f1 = *(const float4*)&s[i + 4];
    *(ushort4*)&d[i]     = make_ushort4(f2bf(f0.x), f2bf(f0.y), f2bf(f0.z), f2bf(f0.w));
    *(ushort4*)&d[i + 4] = make_ushort4(f2bf(f1.x), f2bf(f1.y), f2bf(f1.z), f2bf(f1.w));
}

// ---------------------------------------------------------------------------
// 128x128 counted-vmcnt bf16 NT GEMM (R8 sync skeleton, re-parameterized for
// 2 blocks/CU): out = (X@W^T + bias) * scale
//   mode 0: bf16 out [B=4,H=16,S=2048,64]; mode 2: fp32 out [8192,1024].
// R10 theory: every prior gemm variant ran 1 block/CU (96-128KB LDS) -> no
// co-resident block to overlap barrier/stage phases (m114 overlap missing).
// BM=BN=128, BK=64 -> LDS 64KB -> 2 blocks/CU (launch_bounds(512,4)).
// 512 thr = 8 waves (2Mx4N), per-wave 64x32 out = acc[4][2]. Grids: QKV
// 512 wgs/z = 3 exact rounds @2/CU; out 512 = 1 round @2/CU w/ overlap.
// Issue units per tile: B0,B1,A0,A1, each 64 rows x 64k = 8KB = 1 load/thr.
// Phase p: {issue 1 unit || ds_read A-rowblock p (+4 B-frag reads at p0)} ->
// barrier -> lgkmcnt(0) -> setprio(1) -> 4 MFMA -> setprio(0) ->
// [p3: vmcnt] -> barrier.   vmcnt ledger (1 load/unit): prologue 6 issued,
// vmcnt(2) lands tile0, leaves tile1 B0,B1. Tile t: p0..p3 issue t+1 A0,
// t+1 A1, t+2 B0, t+2 B1 -> 6 outstanding at p3 -> vmcnt(2) retires all of
// t+1, leaves t+2 B0,B1. t>=14: issues skipped (s>=64) -> only 4 outstanding
// -> full drain vmcnt(0) (the R6 tail-race fix, kept).
// Bank swizzle: phys 16B-group = logical ^ (row&7) on DMA source and reads
// (row&7 == l16&7 at every read site). XCD: t0=(flat&7)*64+flat>>3, 512%8==0.
// ---------------------------------------------------------------------------
struct GemmArgs {
    const ushort* X[3]; const ushort* W[3]; const float* B[3];
    void* O[3]; int mode[3]; float scale[3];
};

__global__ __launch_bounds__(512, 4) void gemmk(GemmArgs g) {
    extern __shared__ __attribute__((aligned(16))) ushort smem[];
    // A: [0, 16384) ushorts (2 bufs x 8192); B: [16384, 32768) (2 x 8192).

    const int z = blockIdx.z;
    const ushort* __restrict__ X = g.X[z];
    const ushort* __restrict__ W = g.W[z];
    const float*  __restrict__ bias = g.B[z];
    const int mode = g.mode[z];
    const float scale = g.scale[z];

    const int tid  = threadIdx.x;
    const int lane = tid & 63;
    const int wave = tid >> 6;
    const int quad = (lane >> 4) & 3;
    const int l16  = lane & 15;
    const int wm   = (wave >> 2) * 64;   // 2 M-waves: 64 rows each
    const int wn   = (wave & 3) * 32;    // 4 N-waves: 32 cols each

    const int flat = blockIdx.x + 8 * blockIdx.y;     // 0..511, xcd = flat%8
    const int t0   = (flat & 7) * 64 + (flat >> 3);   // bijective (512%8==0)
    const int m0   = (t0 >> 3) * 128;
    const int n0   = (t0 & 7) * 128;

    f32x4 acc[4][2];
#pragma unroll
    for (int i = 0; i < 4; i++)
#pragma unroll
        for (int j = 0; j < 2; j++) acc[i][j] = (f32x4)0.0f;

    // seq s -> tile s>>2, kind s&3 (0,1 = B half, 2,3 = A half). 1 load/thr.
    auto issue = [&](int s) {
        if (s >= 64) return;
        const int tile = s >> 2;
        const int buf  = tile & 1;
        const int kind = s & 3;
        const int k0   = tile * 64;
        const int row  = tid >> 3;           // 0..63
        const int gp   = (tid & 7) ^ (row & 7);
        if (kind < 2) {
            ASYNC16(&W[(size_t)(n0 + kind * 64 + row) * 1024 + k0 + gp * 8],
                    smem + 16384 + buf * 8192 + kind * 4096 + wave * 512);
        } else {
            const int half = kind - 2;
            ASYNC16(&X[(size_t)(m0 + half * 64 + row) * 1024 + k0 + gp * 8],
                    smem + buf * 8192 + half * 4096 + wave * 512);
        }
    };

    // Prologue: tile0 (4 loads) + tile1 B0,B1 (2); land tile0.
    for (int s = 0; s < 6; s++) issue(s);
    asm volatile("s_waitcnt vmcnt(2)" ::: "memory");
    __builtin_amdgcn_sched_barrier(0);
    __builtin_amdgcn_s_barrier();

    const int sw = l16 & 7;

    for (int t = 0; t < 16; t++) {
        const ushort* A  = smem + (t & 1) * 8192;
        const ushort* Bm = smem + 16384 + (t & 1) * 8192;
        bf16x8 bfrag[2][2];
#pragma unroll
        for (int p = 0; p < 4; p++) {
            issue(4 * t + p + 6);
            if (p == 0) {
#pragma unroll
                for (int nj = 0; nj < 2; nj++)
#pragma unroll
                    for (int ks = 0; ks < 2; ks++) {
                        const int br = wn + nj * 16 + l16;
                        bfrag[nj][ks] = *(const bf16x8*)
                            &Bm[(size_t)(br >> 6) * 4096 + (br & 63) * 64
                                + (((ks * 4 + quad) ^ sw) * 8)];
                    }
            }
            bf16x8 af[2];
#pragma unroll
            for (int ks = 0; ks < 2; ks++) {
                const int ar = wm + p * 16 + l16;
                af[ks] = *(const bf16x8*)
                    &A[(size_t)(ar >> 6) * 4096 + (ar & 63) * 64
                       + (((ks * 4 + quad) ^ sw) * 8)];
            }
            __builtin_amdgcn_s_barrier();
            asm volatile("s_waitcnt lgkmcnt(0)" ::: "memory");
            __builtin_amdgcn_sched_barrier(0);
            __builtin_amdgcn_s_setprio(1);
#pragma unroll
            for (int nj = 0; nj < 2; nj++) {
                acc[p][nj] = MFMA32(af[0], bfrag[nj][0], acc[p][nj]);
                acc[p][nj] = MFMA32(af[1], bfrag[nj][1], acc[p][nj]);
            }
            __builtin_amdgcn_s_setprio(0);
            if (p == 3) {
                if (t < 14) {
                    // tile t+1 fully landed; t+2's B0,B1 stay in flight.
                    asm volatile("s_waitcnt vmcnt(2)" ::: "memory");
                } else {
                    // issue stream exhausted: full drain (tail-race fix).
                    asm volatile("s_waitcnt vmcnt(0)" ::: "memory");
                }
                __builtin_amdgcn_sched_barrier(0);
            }
            __builtin_amdgcn_s_barrier();
        }
    }

    // C/D: col = lane&15 (n), row = quad*4 + reg (m).
#pragma unroll
    for (int mi = 0; mi < 4; mi++) {
#pragma unroll
        for (int nj = 0; nj < 2; nj++) {
            const int n  = n0 + wn + nj * 16 + l16;
            const float bb = bias[n];
#pragma unroll
            for (int r = 0; r < 4; r++) {
                const int m = m0 + wm + mi * 16 + quad * 4 + r;
                const float val = (acc[mi][nj][r] + bb) * scale;
                if (mode == 2) {
                    ((float*)g.O[z])[(size_t)m * 1024 + n] = val;
                } else {
                    const int bat = m >> 11, s = m & 2047, h = n >> 6, d = n & 63;
                    ((ushort*)g.O[z])[((size_t)((bat * 16 + h) * 2048 + s)) * 64 + d]
                        = f2bf(val);
                }
            }
        }
    }
}

// ---------------------------------------------------------------------------
// Attention — VERBATIM R8 version (harness-passed at ~90 us; at ~98% combined
// MFMA+VALU issue = structural ceiling). st=2, wave owns 32 q-rows, grid
// 1024, 4 blocks/CU. All R6/R7/R9 attn edits abandoned (unexplained fails).
// ---------------------------------------------------------------------------
__global__ __launch_bounds__(256, 4) void attn(
    const ushort* __restrict__ Qp, const ushort* __restrict__ Kp,
    const ushort* __restrict__ Vp, ushort* __restrict__ ctx)
{
    __shared__ __attribute__((aligned(16))) ushort Ks[2][2 * 64 * 32];  // 2x8KB
    __shared__ __attribute__((aligned(16))) ushort Vs[2][64 * 64];      // 2x8KB

    const int tid  = threadIdx.x;
    const int lane = tid & 63;
    const int wave = tid >> 6;
    const int quad = lane >> 4;
    const int l16  = lane & 15;

    const int id = blockIdx.x;
    const int bh = (id & 7) * 8 + ((id >> 3) & 7);  // XCD-contiguous bh
    const int q0 = (id >> 6) * 128;
    const int b  = bh >> 4, h = bh & 15;

    const ushort* Qg = Qp + ((size_t)bh * 2048 + q0) * 64;
    const ushort* Kg = Kp + (size_t)bh * 2048 * 64;
    const ushort* Vg = Vp + (size_t)bh * 2048 * 64;

    // Loop-invariant Q fragments (B-operand: n=l16=query, k=quad*8+e).
    bf16x8 aq[2][2];
#pragma unroll
    for (int st = 0; st < 2; st++)
#pragma unroll
        for (int kk = 0; kk < 2; kk++)
            aq[st][kk] = *(const bf16x8*)&Qg[(size_t)(wave * 32 + st * 16 + l16) * 64
                                            + kk * 32 + quad * 8];

    f32x4 o[2][4];
#pragma unroll
    for (int st = 0; st < 2; st++)
#pragma unroll
        for (int jd = 0; jd < 4; jd++) o[st][jd] = (f32x4)0.0f;
#if HAVE_MFMA16K
    f32x4 ls[2] = {(f32x4)0.0f, (f32x4)0.0f};  // row sums, o-compatible layout
    union { uint u[2]; bf16x4 v; } ones;
    ones.u[0] = 0x3F803F80u; ones.u[1] = 0x3F803F80u;  // bf16 1.0 x4
#else
    float lsum[2] = {0.f, 0.f};
#endif

    // K tile: natural [half][row][32] layout. V tile: 4x16-subtiled V' via
    // source-swizzled async chunks; global src stays 128B-coalesced per 8 lanes.
    auto stage = [&](int buf, int n0) {
#pragma unroll
        for (int j = 0; j < 2; j++) {
            const int c    = j * 256 + tid;
            const int colq = c & 3;
            const int row  = (c >> 2) & 63;
            const int half = c >> 8;
            ASYNC16(&Kg[(size_t)(n0 + row) * 64 + half * 32 + colq * 8],
                    &Ks[buf][0] + (size_t)(j * 256 + wave * 64) * 8);
        }
#pragma unroll
        for (int j = 0; j < 2; j++) {
            const int c   = j * 256 + tid;
            const int key = ((c >> 5) << 2) | ((c >> 1) & 3);
            const int d   = (((c >> 3) & 3) << 4) | ((c & 1) << 3);
            ASYNC16(&Vg[(size_t)(n0 + key) * 64 + d],
                    &Vs[buf][0] + (size_t)(j * 256 + wave * 64) * 8);
        }
    };

    stage(0, 0);
    int cur = 0;

    for (int n0 = 0; n0 < 2048; n0 += 64) {
        __syncthreads();  // drains vmcnt: buf 'cur' is ready; prev reads done
        if (n0 + 64 < 2048) stage(cur ^ 1, n0 + 64);  // flies under compute

        // ---- S^T: 8 tiles (kb keys x st strips), exp2 + pack in-register ----
        uint pk[4][2][2];
#pragma unroll
        for (int kb = 0; kb < 4; kb++) {
            bf16x8 kf0 = *(const bf16x8*)&Ks[cur][(size_t)(kb * 16 + l16) * 32 + quad * 8];
            bf16x8 kf1 = *(const bf16x8*)&Ks[cur][(size_t)(64 + kb * 16 + l16) * 32 + quad * 8];
#pragma unroll
            for (int st = 0; st < 2; st++) {
                f32x4 s = (f32x4)0.0f;
                s = MFMA32(kf0, aq[st][0], s);
                s = MFMA32(kf1, aq[st][1], s);
                float e0 = __builtin_amdgcn_exp2f(s[0]);
                float e1 = __builtin_amdgcn_exp2f(s[1]);
                float e2 = __builtin_amdgcn_exp2f(s[2]);
                float e3 = __builtin_amdgcn_exp2f(s[3]);
                pk[kb][st][0] = cvtpk(e0, e1);
                pk[kb][st][1] = cvtpk(e2, e3);
#if !HAVE_MFMA16K
                lsum[st] += (e0 + e1) + (e2 + e3);
#endif
            }
        }

#if HAVE_MFMA16K
        // ---- PV: B-frags via hw transpose reads from subtiled V' ----
        const lds_ushort* vp = (const lds_ushort*)&Vs[cur][0] + quad * 256 + l16 * 4;
        bf16x4 vf[4][4];  // [jd][kb]
#define TRISSUE(JD)                                                            \
        TR16(vf[JD][0], vp, (JD) * 128 + 0);                                   \
        TR16(vf[JD][1], vp, (JD) * 128 + 2048);                                \
        TR16(vf[JD][2], vp, (JD) * 128 + 4096);                                \
        TR16(vf[JD][3], vp, (JD) * 128 + 6144);
        TRISSUE(0) TRISSUE(1) TRISSUE(2) TRISSUE(3)

        // Row-sum MFMAs (register-only) fill the tr-read latency window.
#pragma unroll
        for (int kb = 0; kb < 4; kb++) {
#pragma unroll
            for (int st = 0; st < 2; st++) {
                union { uint u[2]; bf16x4 v; } pf;
                pf.u[0] = pk[kb][st][0];
                pf.u[1] = pk[kb][st][1];
                ls[st] = MFMA16K(pf.v, ones.v, ls[st]);
            }
        }

        // counted lgkmcnt: jd group ready when <=12-4*jd outstanding (FIFO,
        // trs are oldest). sched_barrier(0) after each wait (rule #18).
#define PVWAIT(N)                                                              \
        asm volatile("s_waitcnt lgkmcnt(" #N ")" ::: "memory");                \
        __builtin_amdgcn_sched_barrier(0);
#define PVJD(JD)                                                               \
        _Pragma("unroll")                                                      \
        for (int kb = 0; kb < 4; kb++) {                                       \
            _Pragma("unroll")                                                  \
            for (int st = 0; st < 2; st++) {                                   \
                union { uint u[2]; bf16x4 v; } pf;                             \
                pf.u[0] = pk[kb][st][0];                                       \
                pf.u[1] = pk[kb][st][1];                                       \
                o[st][JD] = MFMA16K(pf.v, vf[JD][kb], o[st][JD]);              \
            }                                                                  \
        }
        __builtin_amdgcn_s_setprio(1);
        PVWAIT(12) PVJD(0)
        PVWAIT(8)  PVJD(1)
        PVWAIT(4)  PVJD(2)
        PVWAIT(0)  PVJD(3)
        __builtin_amdgcn_s_setprio(0);
#else
        // Fallback: assemble K=32 A-frags via ds_bpermute, gather V from the
        // subtiled V' with scalar reads, PV with MFMA32. (Correctness path.)
        const int addr0 = 4 * ((2 * (quad & 1)) * 16 + l16);
        const int addr1 = addr0 + 64;
#pragma unroll
        for (int kt = 0; kt < 2; kt++) {
            bf16x8 apf[2];
#pragma unroll
            for (int st = 0; st < 2; st++) {
                union { uint u[4]; bf16x8 v; } t;
#pragma unroll
                for (int j = 0; j < 4; j++) {
                    uint src = (quad & 2) ? pk[kt * 2 + 1][st][j & 1]
                                          : pk[kt * 2][st][j & 1];
                    t.u[j] = (uint)__builtin_amdgcn_ds_bpermute(
                        (j >> 1) ? addr1 : addr0, (int)src);
                }
                apf[st] = t.v;
            }
#pragma unroll
            for (int jd = 0; jd < 4; jd++) {
                union { ushort s[8]; bf16x8 v; } vv;
#pragma unroll
                for (int e = 0; e < 8; e++) {
                    const int key = kt * 32 + quad * 8 + e;
                    const int d   = jd * 16 + l16;
                    vv.s[e] = Vs[cur][(key >> 2) * 256 + (d >> 4) * 64
                                      + (key & 3) * 16 + (d & 15)];
                }
#pragma unroll
                for (int st = 0; st < 2; st++)
                    o[st][jd] = MFMA32(apf[st], vv.v, o[st][jd]);
            }
        }
#endif
        cur ^= 1;
    }

#if HAVE_MFMA16K
    // ls[st][r] is already the row sum for query quad*4+r — no shuffles.
#pragma unroll
    for (int st = 0; st < 2; st++) {
        float inv[4];
#pragma unroll
        for (int r = 0; r < 4; r++) inv[r] = 1.0f / ls[st][r];
#pragma unroll
        for (int jd = 0; jd < 4; jd++) {
#pragma unroll
            for (int r = 0; r < 4; r++) {
                const int s = q0 + wave * 32 + st * 16 + quad * 4 + r;
                ctx[((size_t)(b * 2048 + s)) * 1024 + h * 64 + jd * 16 + l16] =
                    f2bf(o[st][jd][r] * inv[r]);
            }
        }
    }
#else
    // lsum holds per-(l16,quad) partials for query=l16: reduce over quads.
#pragma unroll
    for (int st = 0; st < 2; st++) {
        float lsv = lsum[st];
        lsv += __shfl_xor(lsv, 16, 64);
        lsv += __shfl_xor(lsv, 32, 64);
        float inv[4];
#pragma unroll
        for (int r = 0; r < 4; r++)
            inv[r] = 1.0f / __shfl(lsv, quad * 4 + r, 64);
#pragma unroll
        for (int jd = 0; jd < 4; jd++) {
#pragma unroll
            for (int r = 0; r < 4; r++) {
                const int s = q0 + wave * 32 + st * 16 + quad * 4 + r;
                ctx[((size_t)(b * 2048 + s)) * 1024 + h * 64 + jd * 16 + l16] =
                    f2bf(o[st][jd][r] * inv[r]);
            }
        }
    }
#endif
}

extern "C" void kernel_launch(void* const* d_in, const int* in_sizes, int n_in,
                              void* d_out, int out_size, void* d_ws, size_t ws_size,
                              hipStream_t stream) {
    const float* q    = (const float*)d_in[0];
    const float* k    = (const float*)d_in[1];
    const float* v    = (const float*)d_in[2];
    const float* wq_w = (const float*)d_in[3];
    const float* wq_b = (const float*)d_in[4];
    const float* wk_w = (const float*)d_in[5];
    const float* wk_b = (const float*)d_in[6];
    const float* wv_w = (const float*)d_in[7];
    const float* wv_b = (const float*)d_in[8];
    const float* wo_w = (const float*)d_in[9];
    const float* wo_b = (const float*)d_in[10];
    float* out = (float*)d_out;

    const size_t NE = (size_t)4 * 2048 * 1024;
    const size_t NW = (size_t)1024 * 1024;
    const size_t need_fused = (6 * NE + 4 * NW) * 2;
    const size_t LDSB = 65536;  // 64KB dynamic LDS for gemmk -> 2 blocks/CU

    dim3 blk(256);
    dim3 gblk(512);
    dim3 ggrid(8, 64, 3);   // 512 wgs/z: 64 m-tiles x 8 n-tiles
    dim3 ggrid1(8, 64, 1);

    if (ws_size >= need_fused) {
        ushort* Xq = (ushort*)d_ws;
        ushort* Xk = Xq + NE;
        ushort* Xv = Xk + NE;
        ushort* Wq = Xv + NE;
        ushort* Wk = Wq + NW;
        ushort* Wv = Wk + NW;
        ushort* Wo = Wv + NW;
        ushort* Qp = Wo + NW;
        ushort* Kp = Qp + NE;
        ushort* Vp = Kp + NE;
        ushort* ctx = Xq;

        CvtArgs ca;
        ca.s[0]=q;    ca.d[0]=Xq; ca.nb[0]=4096;
        ca.s[1]=k;    ca.d[1]=Xk; ca.nb[1]=4096;
        ca.s[2]=v;    ca.d[2]=Xv; ca.nb[2]=4096;
        ca.s[3]=wq_w; ca.d[3]=Wq; ca.nb[3]=512;
        ca.s[4]=wk_w; ca.d[4]=Wk; ca.nb[4]=512;
        ca.s[5]=wv_w; ca.d[5]=Wv; ca.nb[5]=512;
        ca.s[6]=wo_w; ca.d[6]=Wo; ca.nb[6]=512;
        cvtk<<<dim3(4096, 7), blk, 0, stream>>>(ca);

        GemmArgs ga;
        ga.X[0]=Xq; ga.W[0]=Wq; ga.B[0]=wq_b; ga.O[0]=Qp; ga.mode[0]=0; ga.scale[0]=QSCALE;
        ga.X[1]=Xk; ga.W[1]=Wk; ga.B[1]=wk_b; ga.O[1]=Kp; ga.mode[1]=0; ga.scale[1]=1.0f;
        ga.X[2]=Xv; ga.W[2]=Wv; ga.B[2]=wv_b; ga.O[2]=Vp; ga.mode[2]=0; ga.scale[2]=1.0f;
        gemmk<<<ggrid, gblk, LDSB, stream>>>(ga);

        attn<<<dim3(1024), blk, 0, stream>>>(Qp, Kp, Vp, ctx);

        GemmArgs go;
        for (int i = 0; i < 3; i++) {
            go.X[i]=ctx; go.W[i]=Wo; go.B[i]=wo_b;
            go.O[i]=out; go.mode[i]=2; go.scale[i]=1.0f;
        }
        gemmk<<<ggrid1, gblk, LDSB, stream>>>(go);
    } else {
        // Serial fallback: Xb reused per projection, then as ctx (68 MB).
        ushort* Xb  = (ushort*)d_ws;
        ushort* Wb  = Xb + NE;
        ushort* Wob = Wb + NW;
        ushort* Qp  = Wob + NW;
        ushort* Kp  = Qp + NE;
        ushort* Vp  = Kp + NE;
        ushort* ctx = Xb;

        const float* xs[3] = {q, k, v};
        const float* ws[3] = {wq_w, wk_w, wv_w};
        const float* bs[3] = {wq_b, wk_b, wv_b};
        ushort* os[3] = {Qp, Kp, Vp};
        for (int p = 0; p < 3; p++) {
            CvtArgs c;
            c.s[0]=xs[p]; c.d[0]=Xb; c.nb[0]=4096;
            c.s[1]=ws[p]; c.d[1]=Wb; c.nb[1]=512;
            for (int i = 2; i < 7; i++) { c.s[i]=xs[p]; c.d[i]=Xb; c.nb[i]=0; }
            cvtk<<<dim3(4096, 2), blk, 0, stream>>>(c);
            GemmArgs gg;
            for (int i = 0; i < 3; i++) {
                gg.X[i]=Xb; gg.W[i]=Wb; gg.B[i]=bs[p]; gg.O[i]=os[p];
                gg.mode[i]=0; gg.scale[i]=(p == 0) ? QSCALE : 1.0f;
            }
            gemmk<<<ggrid1, gblk, LDSB, stream>>>(gg);
        }

        attn<<<dim3(1024), blk, 0, stream>>>(Qp, Kp, Vp, ctx);

        CvtArgs c;
        c.s[0]=wo_w; c.d[0]=Wob; c.nb[0]=512;
        for (int i = 1; i < 7; i++) { c.s[i]=wo_w; c.d[i]=Wob; c.nb[i]=0; }
        cvtk<<<dim3(512, 1), blk, 0, stream>>>(c);
        GemmArgs go;
        for (int i = 0; i < 3; i++) {
            go.X[i]=ctx; go.W[i]=Wob; go.B[i]=wo_b;
            go.O[i]=out; go.mode[i]=2; go.scale[i]=1.0f;
        }
        gemmk<<<ggrid1, gblk, LDSB, stream>>>(go);
    }
}

// Round 12
// 307.419 us; speedup vs baseline: 1.2761x; 1.0610x over previous
//
#include <hip/hip_runtime.h>
#include <hip/hip_bf16.h>

typedef __attribute__((ext_vector_type(8))) short bf16x8;
typedef __attribute__((ext_vector_type(4))) short bf16x4;
typedef __attribute__((ext_vector_type(4))) float f32x4;
typedef __attribute__((address_space(3))) ushort lds_ushort;

#define MFMA32(a, b, c) __builtin_amdgcn_mfma_f32_16x16x32_bf16(a, b, c, 0, 0, 0)
#if __has_builtin(__builtin_amdgcn_mfma_f32_16x16x16bf16_1k)
#define HAVE_MFMA16K 1
#define MFMA16K(a, b, c) __builtin_amdgcn_mfma_f32_16x16x16bf16_1k(a, b, c, 0, 0, 0)
#else
#define HAVE_MFMA16K 0
#endif

// async global->LDS, 16B/lane; LDS dest = wave-uniform base + lane*16.
#define ASYNC16(g, l)                                                          \
    __builtin_amdgcn_global_load_lds(                                          \
        (const __attribute__((address_space(1))) unsigned int*)(g),            \
        (__attribute__((address_space(3))) unsigned int*)(l), 16, 0, 0)

// hw transpose read: per 16-lane group reads 128B window as 4x16 bf16
// row-major, lane l gets column (l&15). addr = window_base + (l&15)*8 bytes.
#define TR16(dst, addr, OFF)                                                   \
    asm volatile("ds_read_b64_tr_b16 %0, %1 offset:%2"                         \
                 : "=v"(dst) : "v"(addr), "i"(OFF))

__device__ __forceinline__ ushort f2bf(float f) {
    __hip_bfloat16 h = __float2bfloat16(f);  // RNE
    return *reinterpret_cast<ushort*>(&h);
}
// pack two f32 to bf16 pair in one instruction (T12; no builtin on gfx950).
__device__ __forceinline__ uint cvtpk(float a, float b) {
    uint r;
    asm("v_cvt_pk_bf16_f32 %0, %1, %2" : "=v"(r) : "v"(a), "v"(b));
    return r;
}

// log2(e)/sqrt(64), folded into Q projection -> attn does exp2(score) raw.
#define QSCALE 0.18033688011112042f

// ---------------------------------------------------------------------------
// fp32 -> bf16 convert, multi-range (q,k,v + 4 weights).
// ---------------------------------------------------------------------------
struct CvtArgs { const float* s[7]; ushort* d[7]; int nb[7]; };

__global__ __launch_bounds__(256) void cvtk(CvtArgs a) {
    const int z = blockIdx.y;
    if ((int)blockIdx.x >= a.nb[z]) return;
    const float* s = a.s[z];
    ushort* d = a.d[z];
    const size_t i = (size_t)blockIdx.x * 2048 + threadIdx.x * 8;
    float4 f0 = *(const float4*)&s[i];
    float4 f1 = *(const float4*)&s[i + 4];
    *(ushort4*)&d[i]     = make_ushort4(f2bf(f0.x), f2bf(f0.y), f2bf(f0.z), f2bf(f0.w));
    *(ushort4*)&d[i + 4] = make_ushort4(f2bf(f1.x), f2bf(f1.y), f2bf(f1.z), f2bf(f1.w));
}

// ---------------------------------------------------------------------------
// 128x128 counted-vmcnt bf16 NT GEMM: out = (X@W^T + bias) * scale
//   mode 0: bf16 out [B=4,H=16,S=2048,64]; mode 2: fp32 out [8192,1024].
// R10 skeleton (harness-passed) with R11 change: 2 phases/tile x 8 MFMA
// (was 4 phases x 4 MFMA) — R10's 4-MFMA phases were barrier-overhead-
// dominated (~32 MFMA-cyc between 2 barriers). BM=BN=128, BK=64, LDS 64KB
// -> 2 blocks/CU (launch_bounds(512,4)); 8 waves (2Mx4N), acc[4][2].
// Phase p in {0,1}: {issue 2 units || ds_read 2 A-rowblocks (+4 B-frags at
// p0)} -> barrier -> lgkmcnt(0) -> setprio(1) -> 8 MFMA -> setprio(0) ->
// [p1: vmcnt] -> barrier.
// vmcnt ledger (1 load/unit; units per tile B0,B1,A0,A1 = seq 4t..4t+3):
// entering tile t: 2 in flight (t+1 B0,B1). p0 issues s=4t+6,4t+7 = t+1
// A0,A1 (opposite buf, safe) -> 4. p1 issues s=4t+8,4t+9 = t+2 B0,B1 (same
// buf; safe: p0-end barrier guarantees all waves drained their B-frag
// lgkmcnt(0) first) -> 6. vmcnt(2) at p1 retires exactly tile t+1, leaves
// t+2 B0,B1. t>=14: issue stream exhausted (s>=64) -> full drain vmcnt(0)
// (tail-race rule from R7). Bank swizzle: phys 16B-group = logical^(row&7)
// on DMA source and reads. XCD: t0=(flat&7)*64+flat>>3 (512%8==0).
// ---------------------------------------------------------------------------
struct GemmArgs {
    const ushort* X[3]; const ushort* W[3]; const float* B[3];
    void* O[3]; int mode[3]; float scale[3];
};

__global__ __launch_bounds__(512, 4) void gemmk(GemmArgs g) {
    extern __shared__ __attribute__((aligned(16))) ushort smem[];
    // A: [0, 16384) ushorts (2 bufs x 8192); B: [16384, 32768) (2 x 8192).

    const int z = blockIdx.z;
    const ushort* __restrict__ X = g.X[z];
    const ushort* __restrict__ W = g.W[z];
    const float*  __restrict__ bias = g.B[z];
    const int mode = g.mode[z];
    const float scale = g.scale[z];

    const int tid  = threadIdx.x;
    const int lane = tid & 63;
    const int wave = tid >> 6;
    const int quad = (lane >> 4) & 3;
    const int l16  = lane & 15;
    const int wm   = (wave >> 2) * 64;   // 2 M-waves: 64 rows each
    const int wn   = (wave & 3) * 32;    // 4 N-waves: 32 cols each

    const int flat = blockIdx.x + 8 * blockIdx.y;     // 0..511, xcd = flat%8
    const int t0   = (flat & 7) * 64 + (flat >> 3);   // bijective (512%8==0)
    const int m0   = (t0 >> 3) * 128;
    const int n0   = (t0 & 7) * 128;

    f32x4 acc[4][2];
#pragma unroll
    for (int i = 0; i < 4; i++)
#pragma unroll
        for (int j = 0; j < 2; j++) acc[i][j] = (f32x4)0.0f;

    // seq s -> tile s>>2, kind s&3 (0,1 = B half, 2,3 = A half). 1 load/thr.
    auto issue = [&](int s) {
        if (s >= 64) return;
        const int tile = s >> 2;
        const int buf  = tile & 1;
        const int kind = s & 3;
        const int k0   = tile * 64;
        const int row  = tid >> 3;           // 0..63
        const int gp   = (tid & 7) ^ (row & 7);
        if (kind < 2) {
            ASYNC16(&W[(size_t)(n0 + kind * 64 + row) * 1024 + k0 + gp * 8],
                    smem + 16384 + buf * 8192 + kind * 4096 + wave * 512);
        } else {
            const int half = kind - 2;
            ASYNC16(&X[(size_t)(m0 + half * 64 + row) * 1024 + k0 + gp * 8],
                    smem + buf * 8192 + half * 4096 + wave * 512);
        }
    };

    // Prologue: tile0 (4 loads) + tile1 B0,B1 (2); land tile0.
    for (int s = 0; s < 6; s++) issue(s);
    asm volatile("s_waitcnt vmcnt(2)" ::: "memory");
    __builtin_amdgcn_sched_barrier(0);
    __builtin_amdgcn_s_barrier();

    const int sw = l16 & 7;

    for (int t = 0; t < 16; t++) {
        const ushort* A  = smem + (t & 1) * 8192;
        const ushort* Bm = smem + 16384 + (t & 1) * 8192;
        bf16x8 bfrag[2][2];
#pragma unroll
        for (int p = 0; p < 2; p++) {
            issue(4 * t + 2 * p + 6);
            issue(4 * t + 2 * p + 7);
            if (p == 0) {
#pragma unroll
                for (int nj = 0; nj < 2; nj++)
#pragma unroll
                    for (int ks = 0; ks < 2; ks++) {
                        const int br = wn + nj * 16 + l16;
                        bfrag[nj][ks] = *(const bf16x8*)
                            &Bm[(size_t)(br >> 6) * 4096 + (br & 63) * 64
                                + (((ks * 4 + quad) ^ sw) * 8)];
                    }
            }
            bf16x8 af[2][2];
#pragma unroll
            for (int i = 0; i < 2; i++)
#pragma unroll
                for (int ks = 0; ks < 2; ks++) {
                    const int ar = wm + (2 * p + i) * 16 + l16;
                    af[i][ks] = *(const bf16x8*)
                        &A[(size_t)(ar >> 6) * 4096 + (ar & 63) * 64
                           + (((ks * 4 + quad) ^ sw) * 8)];
                }
            __builtin_amdgcn_s_barrier();
            asm volatile("s_waitcnt lgkmcnt(0)" ::: "memory");
            __builtin_amdgcn_sched_barrier(0);
            __builtin_amdgcn_s_setprio(1);
#pragma unroll
            for (int i = 0; i < 2; i++)
#pragma unroll
                for (int nj = 0; nj < 2; nj++) {
                    acc[2 * p + i][nj] = MFMA32(af[i][0], bfrag[nj][0],
                                                acc[2 * p + i][nj]);
                    acc[2 * p + i][nj] = MFMA32(af[i][1], bfrag[nj][1],
                                                acc[2 * p + i][nj]);
                }
            __builtin_amdgcn_s_setprio(0);
            if (p == 1) {
                if (t < 14) {
                    // tile t+1 fully landed; t+2's B0,B1 stay in flight.
                    asm volatile("s_waitcnt vmcnt(2)" ::: "memory");
                } else {
                    // issue stream exhausted: full drain (tail-race fix).
                    asm volatile("s_waitcnt vmcnt(0)" ::: "memory");
                }
                __builtin_amdgcn_sched_barrier(0);
            }
            __builtin_amdgcn_s_barrier();
        }
    }

    // C/D: col = lane&15 (n), row = quad*4 + reg (m).
#pragma unroll
    for (int mi = 0; mi < 4; mi++) {
#pragma unroll
        for (int nj = 0; nj < 2; nj++) {
            const int n  = n0 + wn + nj * 16 + l16;
            const float bb = bias[n];
#pragma unroll
            for (int r = 0; r < 4; r++) {
                const int m = m0 + wm + mi * 16 + quad * 4 + r;
                const float val = (acc[mi][nj][r] + bb) * scale;
                if (mode == 2) {
                    ((float*)g.O[z])[(size_t)m * 1024 + n] = val;
                } else {
                    const int bat = m >> 11, s = m & 2047, h = n >> 6, d = n & 63;
                    ((ushort*)g.O[z])[((size_t)((bat * 16 + h) * 2048 + s)) * 64 + d]
                        = f2bf(val);
                }
            }
        }
    }
}

// ---------------------------------------------------------------------------
// Attention — VERBATIM R8/R10 version (harness-passed at ~91 us; ~97%
// combined MFMA+VALU issue = structural ceiling). st=2, grid 1024, 4/CU.
// ---------------------------------------------------------------------------
__global__ __launch_bounds__(256, 4) void attn(
    const ushort* __restrict__ Qp, const ushort* __restrict__ Kp,
    const ushort* __restrict__ Vp, ushort* __restrict__ ctx)
{
    __shared__ __attribute__((aligned(16))) ushort Ks[2][2 * 64 * 32];  // 2x8KB
    __shared__ __attribute__((aligned(16))) ushort Vs[2][64 * 64];      // 2x8KB

    const int tid  = threadIdx.x;
    const int lane = tid & 63;
    const int wave = tid >> 6;
    const int quad = lane >> 4;
    const int l16  = lane & 15;

    const int id = blockIdx.x;
    const int bh = (id & 7) * 8 + ((id >> 3) & 7);  // XCD-contiguous bh
    const int q0 = (id >> 6) * 128;
    const int b  = bh >> 4, h = bh & 15;

    const ushort* Qg = Qp + ((size_t)bh * 2048 + q0) * 64;
    const ushort* Kg = Kp + (size_t)bh * 2048 * 64;
    const ushort* Vg = Vp + (size_t)bh * 2048 * 64;

    // Loop-invariant Q fragments (B-operand: n=l16=query, k=quad*8+e).
    bf16x8 aq[2][2];
#pragma unroll
    for (int st = 0; st < 2; st++)
#pragma unroll
        for (int kk = 0; kk < 2; kk++)
            aq[st][kk] = *(const bf16x8*)&Qg[(size_t)(wave * 32 + st * 16 + l16) * 64
                                            + kk * 32 + quad * 8];

    f32x4 o[2][4];
#pragma unroll
    for (int st = 0; st < 2; st++)
#pragma unroll
        for (int jd = 0; jd < 4; jd++) o[st][jd] = (f32x4)0.0f;
#if HAVE_MFMA16K
    f32x4 ls[2] = {(f32x4)0.0f, (f32x4)0.0f};  // row sums, o-compatible layout
    union { uint u[2]; bf16x4 v; } ones;
    ones.u[0] = 0x3F803F80u; ones.u[1] = 0x3F803F80u;  // bf16 1.0 x4
#else
    float lsum[2] = {0.f, 0.f};
#endif

    // K tile: natural [half][row][32] layout. V tile: 4x16-subtiled V' via
    // source-swizzled async chunks; global src stays 128B-coalesced per 8 lanes.
    auto stage = [&](int buf, int n0) {
#pragma unroll
        for (int j = 0; j < 2; j++) {
            const int c    = j * 256 + tid;
            const int colq = c & 3;
            const int row  = (c >> 2) & 63;
            const int half = c >> 8;
            ASYNC16(&Kg[(size_t)(n0 + row) * 64 + half * 32 + colq * 8],
                    &Ks[buf][0] + (size_t)(j * 256 + wave * 64) * 8);
        }
#pragma unroll
        for (int j = 0; j < 2; j++) {
            const int c   = j * 256 + tid;
            const int key = ((c >> 5) << 2) | ((c >> 1) & 3);
            const int d   = (((c >> 3) & 3) << 4) | ((c & 1) << 3);
            ASYNC16(&Vg[(size_t)(n0 + key) * 64 + d],
                    &Vs[buf][0] + (size_t)(j * 256 + wave * 64) * 8);
        }
    };

    stage(0, 0);
    int cur = 0;

    for (int n0 = 0; n0 < 2048; n0 += 64) {
        __syncthreads();  // drains vmcnt: buf 'cur' is ready; prev reads done
        if (n0 + 64 < 2048) stage(cur ^ 1, n0 + 64);  // flies under compute

        // ---- S^T: 8 tiles (kb keys x st strips), exp2 + pack in-register ----
        uint pk[4][2][2];
#pragma unroll
        for (int kb = 0; kb < 4; kb++) {
            bf16x8 kf0 = *(const bf16x8*)&Ks[cur][(size_t)(kb * 16 + l16) * 32 + quad * 8];
            bf16x8 kf1 = *(const bf16x8*)&Ks[cur][(size_t)(64 + kb * 16 + l16) * 32 + quad * 8];
#pragma unroll
            for (int st = 0; st < 2; st++) {
                f32x4 s = (f32x4)0.0f;
                s = MFMA32(kf0, aq[st][0], s);
                s = MFMA32(kf1, aq[st][1], s);
                float e0 = __builtin_amdgcn_exp2f(s[0]);
                float e1 = __builtin_amdgcn_exp2f(s[1]);
                float e2 = __builtin_amdgcn_exp2f(s[2]);
                float e3 = __builtin_amdgcn_exp2f(s[3]);
                pk[kb][st][0] = cvtpk(e0, e1);
                pk[kb][st][1] = cvtpk(e2, e3);
#if !HAVE_MFMA16K
                lsum[st] += (e0 + e1) + (e2 + e3);
#endif
            }
        }

#if HAVE_MFMA16K
        // ---- PV: B-frags via hw transpose reads from subtiled V' ----
        const lds_ushort* vp = (const lds_ushort*)&Vs[cur][0] + quad * 256 + l16 * 4;
        bf16x4 vf[4][4];  // [jd][kb]
#define TRISSUE(JD)                                                            \
        TR16(vf[JD][0], vp, (JD) * 128 + 0);                                   \
        TR16(vf[JD][1], vp, (JD) * 128 + 2048);                                \
        TR16(vf[JD][2], vp, (JD) * 128 + 4096);                                \
        TR16(vf[JD][3], vp, (JD) * 128 + 6144);
        TRISSUE(0) TRISSUE(1) TRISSUE(2) TRISSUE(3)

        // Row-sum MFMAs (register-only) fill the tr-read latency window.
#pragma unroll
        for (int kb = 0; kb < 4; kb++) {
#pragma unroll
            for (int st = 0; st < 2; st++) {
                union { uint u[2]; bf16x4 v; } pf;
                pf.u[0] = pk[kb][st][0];
                pf.u[1] = pk[kb][st][1];
                ls[st] = MFMA16K(pf.v, ones.v, ls[st]);
            }
        }

        // counted lgkmcnt: jd group ready when <=12-4*jd outstanding (FIFO,
        // trs are oldest). sched_barrier(0) after each wait (rule #18).
#define PVWAIT(N)                                                              \
        asm volatile("s_waitcnt lgkmcnt(" #N ")" ::: "memory");                \
        __builtin_amdgcn_sched_barrier(0);
#define PVJD(JD)                                                               \
        _Pragma("unroll")                                                      \
        for (int kb = 0; kb < 4; kb++) {                                       \
            _Pragma("unroll")                                                  \
            for (int st = 0; st < 2; st++) {                                   \
                union { uint u[2]; bf16x4 v; } pf;                             \
                pf.u[0] = pk[kb][st][0];                                       \
                pf.u[1] = pk[kb][st][1];                                       \
                o[st][JD] = MFMA16K(pf.v, vf[JD][kb], o[st][JD]);              \
            }                                                                  \
        }
        __builtin_amdgcn_s_setprio(1);
        PVWAIT(12) PVJD(0)
        PVWAIT(8)  PVJD(1)
        PVWAIT(4)  PVJD(2)
        PVWAIT(0)  PVJD(3)
        __builtin_amdgcn_s_setprio(0);
#else
        // Fallback: assemble K=32 A-frags via ds_bpermute, gather V from the
        // subtiled V' with scalar reads, PV with MFMA32. (Correctness path.)
        const int addr0 = 4 * ((2 * (quad & 1)) * 16 + l16);
        const int addr1 = addr0 + 64;
#pragma unroll
        for (int kt = 0; kt < 2; kt++) {
            bf16x8 apf[2];
#pragma unroll
            for (int st = 0; st < 2; st++) {
                union { uint u[4]; bf16x8 v; } t;
#pragma unroll
                for (int j = 0; j < 4; j++) {
                    uint src = (quad & 2) ? pk[kt * 2 + 1][st][j & 1]
                                          : pk[kt * 2][st][j & 1];
                    t.u[j] = (uint)__builtin_amdgcn_ds_bpermute(
                        (j >> 1) ? addr1 : addr0, (int)src);
                }
                apf[st] = t.v;
            }
#pragma unroll
            for (int jd = 0; jd < 4; jd++) {
                union { ushort s[8]; bf16x8 v; } vv;
#pragma unroll
                for (int e = 0; e < 8; e++) {
                    const int key = kt * 32 + quad * 8 + e;
                    const int d   = jd * 16 + l16;
                    vv.s[e] = Vs[cur][(key >> 2) * 256 + (d >> 4) * 64
                                      + (key & 3) * 16 + (d & 15)];
                }
#pragma unroll
                for (int st = 0; st < 2; st++)
                    o[st][jd] = MFMA32(apf[st], vv.v, o[st][jd]);
            }
        }
#endif
        cur ^= 1;
    }

#if HAVE_MFMA16K
    // ls[st][r] is already the row sum for query quad*4+r — no shuffles.
#pragma unroll
    for (int st = 0; st < 2; st++) {
        float inv[4];
#pragma unroll
        for (int r = 0; r < 4; r++) inv[r] = 1.0f / ls[st][r];
#pragma unroll
        for (int jd = 0; jd < 4; jd++) {
#pragma unroll
            for (int r = 0; r < 4; r++) {
                const int s = q0 + wave * 32 + st * 16 + quad * 4 + r;
                ctx[((size_t)(b * 2048 + s)) * 1024 + h * 64 + jd * 16 + l16] =
                    f2bf(o[st][jd][r] * inv[r]);
            }
        }
    }
#else
    // lsum holds per-(l16,quad) partials for query=l16: reduce over quads.
#pragma unroll
    for (int st = 0; st < 2; st++) {
        float lsv = lsum[st];
        lsv += __shfl_xor(lsv, 16, 64);
        lsv += __shfl_xor(lsv, 32, 64);
        float inv[4];
#pragma unroll
        for (int r = 0; r < 4; r++)
            inv[r] = 1.0f / __shfl(lsv, quad * 4 + r, 64);
#pragma unroll
        for (int jd = 0; jd < 4; jd++) {
#pragma unroll
            for (int r = 0; r < 4; r++) {
                const int s = q0 + wave * 32 + st * 16 + quad * 4 + r;
                ctx[((size_t)(b * 2048 + s)) * 1024 + h * 64 + jd * 16 + l16] =
                    f2bf(o[st][jd][r] * inv[r]);
            }
        }
    }
#endif
}

extern "C" void kernel_launch(void* const* d_in, const int* in_sizes, int n_in,
                              void* d_out, int out_size, void* d_ws, size_t ws_size,
                              hipStream_t stream) {
    const float* q    = (const float*)d_in[0];
    const float* k    = (const float*)d_in[1];
    const float* v    = (const float*)d_in[2];
    const float* wq_w = (const float*)d_in[3];
    const float* wq_b = (const float*)d_in[4];
    const float* wk_w = (const float*)d_in[5];
    const float* wk_b = (const float*)d_in[6];
    const float* wv_w = (const float*)d_in[7];
    const float* wv_b = (const float*)d_in[8];
    const float* wo_w = (const float*)d_in[9];
    const float* wo_b = (const float*)d_in[10];
    float* out = (float*)d_out;

    const size_t NE = (size_t)4 * 2048 * 1024;
    const size_t NW = (size_t)1024 * 1024;
    const size_t need_fused = (6 * NE + 4 * NW) * 2;
    const size_t LDSB = 65536;  // 64KB dynamic LDS for gemmk -> 2 blocks/CU

    dim3 blk(256);
    dim3 gblk(512);
    dim3 ggrid(8, 64, 3);   // 512 wgs/z: 64 m-tiles x 8 n-tiles
    dim3 ggrid1(8, 64, 1);

    if (ws_size >= need_fused) {
        ushort* Xq = (ushort*)d_ws;
        ushort* Xk = Xq + NE;
        ushort* Xv = Xk + NE;
        ushort* Wq = Xv + NE;
        ushort* Wk = Wq + NW;
        ushort* Wv = Wk + NW;
        ushort* Wo = Wv + NW;
        ushort* Qp = Wo + NW;
        ushort* Kp = Qp + NE;
        ushort* Vp = Kp + NE;
        ushort* ctx = Xq;

        CvtArgs ca;
        ca.s[0]=q;    ca.d[0]=Xq; ca.nb[0]=4096;
        ca.s[1]=k;    ca.d[1]=Xk; ca.nb[1]=4096;
        ca.s[2]=v;    ca.d[2]=Xv; ca.nb[2]=4096;
        ca.s[3]=wq_w; ca.d[3]=Wq; ca.nb[3]=512;
        ca.s[4]=wk_w; ca.d[4]=Wk; ca.nb[4]=512;
        ca.s[5]=wv_w; ca.d[5]=Wv; ca.nb[5]=512;
        ca.s[6]=wo_w; ca.d[6]=Wo; ca.nb[6]=512;
        cvtk<<<dim3(4096, 7), blk, 0, stream>>>(ca);

        GemmArgs ga;
        ga.X[0]=Xq; ga.W[0]=Wq; ga.B[0]=wq_b; ga.O[0]=Qp; ga.mode[0]=0; ga.scale[0]=QSCALE;
        ga.X[1]=Xk; ga.W[1]=Wk; ga.B[1]=wk_b; ga.O[1]=Kp; ga.mode[1]=0; ga.scale[1]=1.0f;
        ga.X[2]=Xv; ga.W[2]=Wv; ga.B[2]=wv_b; ga.O[2]=Vp; ga.mode[2]=0; ga.scale[2]=1.0f;
        gemmk<<<ggrid, gblk, LDSB, stream>>>(ga);

        attn<<<dim3(1024), blk, 0, stream>>>(Qp, Kp, Vp, ctx);

        GemmArgs go;
        for (int i = 0; i < 3; i++) {
            go.X[i]=ctx; go.W[i]=Wo; go.B[i]=wo_b;
            go.O[i]=out; go.mode[i]=2; go.scale[i]=1.0f;
        }
        gemmk<<<ggrid1, gblk, LDSB, stream>>>(go);
    } else {
        // Serial fallback: Xb reused per projection, then as ctx (68 MB).
        ushort* Xb  = (ushort*)d_ws;
        ushort* Wb  = Xb + NE;
        ushort* Wob = Wb + NW;
        ushort* Qp  = Wob + NW;
        ushort* Kp  = Qp + NE;
        ushort* Vp  = Kp + NE;
        ushort* ctx = Xb;

        const float* xs[3] = {q, k, v};
        const float* ws[3] = {wq_w, wk_w, wv_w};
        const float* bs[3] = {wq_b, wk_b, wv_b};
        ushort* os[3] = {Qp, Kp, Vp};
        for (int p = 0; p < 3; p++) {
            CvtArgs c;
            c.s[0]=xs[p]; c.d[0]=Xb; c.nb[0]=4096;
            c.s[1]=ws[p]; c.d[1]=Wb; c.nb[1]=512;
            for (int i = 2; i < 7; i++) { c.s[i]=xs[p]; c.d[i]=Xb; c.nb[i]=0; }
            cvtk<<<dim3(4096, 2), blk, 0, stream>>>(c);
            GemmArgs gg;
            for (int i = 0; i < 3; i++) {
                gg.X[i]=Xb; gg.W[i]=Wb; gg.B[i]=bs[p]; gg.O[i]=os[p];
                gg.mode[i]=0; gg.scale[i]=(p == 0) ? QSCALE : 1.0f;
            }
            gemmk<<<ggrid1, gblk, LDSB, stream>>>(gg);
        }

        attn<<<dim3(1024), blk, 0, stream>>>(Qp, Kp, Vp, ctx);

        CvtArgs c;
        c.s[0]=wo_w; c.d[0]=Wob; c.nb[0]=512;
        for (int i = 1; i < 7; i++) { c.s[i]=wo_w; c.d[i]=Wob; c.nb[i]=0; }
        cvtk<<<dim3(512, 1), blk, 0, stream>>>(c);
        GemmArgs go;
        for (int i = 0; i < 3; i++) {
            go.X[i]=ctx; go.W[i]=Wob; go.B[i]=wo_b;
            go.O[i]=out; go.mode[i]=2; go.scale[i]=1.0f;
        }
        gemmk<<<ggrid1, gblk, LDSB, stream>>>(go);
    }
}